// Round 1
// baseline (4501.662 us; speedup 1.0000x reference)
//
#include <hip/hip_runtime.h>
#include <stdint.h>

#define EPS_BN 1e-5f

// ---- order-preserving float<->uint mapping for atomic max --------------------
// map:   f>=0 -> bits|0x80000000 ; f<0 -> ~bits. unsigned compare == float compare.
// 0u is below every mapped real float -> doubles as the "empty segment" sentinel.
__device__ __forceinline__ unsigned map_f(float f) {
    unsigned u = __float_as_uint(f);
    return (u & 0x80000000u) ? ~u : (u | 0x80000000u);
}
__device__ __forceinline__ float unmap_f(unsigned m) {
    return (m & 0x80000000u) ? __uint_as_float(m & 0x7FFFFFFFu) : __uint_as_float(~m);
}

// ---- init agg to sentinel 0, zero stats -------------------------------------
extern "C" __global__ __launch_bounds__(256)
void init_kernel(uint4* __restrict__ agg, float* __restrict__ stats, long n4) {
    if (blockIdx.x == 0 && threadIdx.x < 256) stats[threadIdx.x] = 0.0f;
    uint4 z = {0u, 0u, 0u, 0u};
    long i = (long)blockIdx.x * blockDim.x + threadIdx.x;
    long stride = (long)gridDim.x * blockDim.x;
    for (; i < n4; i += stride) agg[i] = z;
}

// ---- scatter max: 32 lanes per edge, float4 (4 feats) per lane --------------
extern "C" __global__ __launch_bounds__(256)
void scatter_max_kernel(const float4* __restrict__ xin, const int* __restrict__ ei,
                        unsigned* __restrict__ agg, int E) {
    int t = blockIdx.x * 256 + threadIdx.x;
    int e = t >> 5;
    if (e >= E) return;
    int f4 = t & 31;
    int src = ei[e];
    int dst = ei[E + e];
    float4 v = xin[(size_t)src * 32 + f4];
    unsigned* p = agg + (size_t)dst * 128 + (size_t)f4 * 4;
    atomicMax(p + 0, map_f(v.x));
    atomicMax(p + 1, map_f(v.y));
    atomicMax(p + 2, map_f(v.z));
    atomicMax(p + 3, map_f(v.w));
}

// ---- fused GEMM: h = unmap(agg) @ Wl + bias + xin @ Wr ----------------------
// BM=64, BN=128 (all cols), BK=32, 256 threads (16x16), 4x8 outputs per thread.
extern "C" __global__ __launch_bounds__(256)
void gemm_kernel(const unsigned* __restrict__ agg, const float* __restrict__ xin,
                 const float* __restrict__ Wl, const float* __restrict__ Wr,
                 const float* __restrict__ bias, float* __restrict__ h, int nrows) {
    __shared__ __align__(16) float As[64][36];   // [row][k], stride 36 keeps 16B alignment
    __shared__ __align__(16) float Bs[32][136];  // [k][col], stride 136 keeps 16B alignment

    const int t = threadIdx.x;
    const int tx = t & 15;         // col group: cols tx*8 .. tx*8+7
    const int ty = t >> 4;         // row group: rows ty*4 .. ty*4+3
    const int tx8 = tx * 8;
    const int ty4 = ty * 4;
    const int blockRow = blockIdx.x * 64;

    float acc[4][8];
#pragma unroll
    for (int j = 0; j < 4; ++j)
#pragma unroll
        for (int c = 0; c < 8; ++c) acc[j][c] = 0.0f;

    for (int kt = 0; kt < 8; ++kt) {
        const int k0 = kt * 32;
        const bool isAgg = (kt < 4);
        const float* W = isAgg ? Wl : Wr;
        const int kw = isAgg ? k0 : (k0 - 128);

        // B tile: 32 rows x 128 cols = 1024 float4, 4 per thread
#pragma unroll
        for (int it = 0; it < 4; ++it) {
            int idx = t + it * 256;
            int kr = idx >> 5, cq = idx & 31;
            float4 w = *(const float4*)&W[(size_t)(kw + kr) * 128 + cq * 4];
            *(float4*)&Bs[kr][cq * 4] = w;
        }
        // A tile: 64 rows x 32 k = 512 float4, 2 per thread
#pragma unroll
        for (int it = 0; it < 2; ++it) {
            int idx = t + it * 256;
            int r = idx >> 3, kq = idx & 7;
            int row_g = blockRow + r;
            float4 a = {0.f, 0.f, 0.f, 0.f};
            if (row_g < nrows) {
                if (isAgg) {
                    uint4 u = *(const uint4*)&agg[(size_t)row_g * 128 + k0 + kq * 4];
                    a.x = u.x ? unmap_f(u.x) : 0.0f;
                    a.y = u.y ? unmap_f(u.y) : 0.0f;
                    a.z = u.z ? unmap_f(u.z) : 0.0f;
                    a.w = u.w ? unmap_f(u.w) : 0.0f;
                } else {
                    a = *(const float4*)&xin[(size_t)row_g * 128 + (k0 - 128) + kq * 4];
                }
            }
            *(float4*)&As[r][kq * 4] = a;
        }
        __syncthreads();

#pragma unroll
        for (int kk = 0; kk < 32; ++kk) {
            float aa[4];
            aa[0] = As[ty4 + 0][kk];
            aa[1] = As[ty4 + 1][kk];
            aa[2] = As[ty4 + 2][kk];
            aa[3] = As[ty4 + 3][kk];
            float4 b0 = *(const float4*)&Bs[kk][tx8];
            float4 b1 = *(const float4*)&Bs[kk][tx8 + 4];
            float bb[8] = {b0.x, b0.y, b0.z, b0.w, b1.x, b1.y, b1.z, b1.w};
#pragma unroll
            for (int j = 0; j < 4; ++j)
#pragma unroll
                for (int c = 0; c < 8; ++c)
                    acc[j][c] = fmaf(aa[j], bb[c], acc[j][c]);
        }
        __syncthreads();
    }

    float4 bv0 = *(const float4*)&bias[tx8];
    float4 bv1 = *(const float4*)&bias[tx8 + 4];
#pragma unroll
    for (int j = 0; j < 4; ++j) {
        int row = blockRow + ty4 + j;
        if (row < nrows) {
            float4 o0, o1;
            o0.x = acc[j][0] + bv0.x; o0.y = acc[j][1] + bv0.y;
            o0.z = acc[j][2] + bv0.z; o0.w = acc[j][3] + bv0.w;
            o1.x = acc[j][4] + bv1.x; o1.y = acc[j][5] + bv1.y;
            o1.z = acc[j][6] + bv1.z; o1.w = acc[j][7] + bv1.w;
            *(float4*)&h[(size_t)row * 128 + tx8] = o0;
            *(float4*)&h[(size_t)row * 128 + tx8 + 4] = o1;
        }
    }
}

// ---- column sums / sumsq for BatchNorm --------------------------------------
extern "C" __global__ __launch_bounds__(256)
void stats_kernel(const float* __restrict__ h, float* __restrict__ stats, int nrows) {
    __shared__ float ssum[256];
    __shared__ float ssq[256];
    int t = threadIdx.x;
    int c = t & 127;
    int rhalf = t >> 7;  // 0 or 1
    float s = 0.f, q = 0.f;
    for (int r = blockIdx.x * 2 + rhalf; r < nrows; r += gridDim.x * 2) {
        float v = h[(size_t)r * 128 + c];
        s += v;
        q += v * v;
    }
    ssum[t] = s;
    ssq[t] = q;
    __syncthreads();
    if (t < 128) {
        atomicAdd(&stats[c], ssum[t] + ssum[t + 128]);
        atomicAdd(&stats[128 + c], ssq[t] + ssq[t + 128]);
    }
}

// ---- finalize: scale/shift ---------------------------------------------------
extern "C" __global__
void finalize_kernel(const float* __restrict__ stats, const float* __restrict__ gamma,
                     const float* __restrict__ beta, float* __restrict__ ss, float inv_n) {
    int c = threadIdx.x;
    if (c < 128) {
        float mu = stats[c] * inv_n;
        float var = stats[128 + c] * inv_n - mu * mu;
        float sc = gamma[c] * rsqrtf(var + EPS_BN);
        ss[c] = sc;
        ss[128 + c] = beta[c] - mu * sc;
    }
}

// ---- apply BN + ReLU in place ------------------------------------------------
extern "C" __global__ __launch_bounds__(256)
void bn_relu_kernel(float4* __restrict__ h, const float* __restrict__ ss, long n4) {
    __shared__ float s_ss[256];
    if (threadIdx.x < 256) s_ss[threadIdx.x] = ss[threadIdx.x];
    __syncthreads();
    long i = (long)blockIdx.x * blockDim.x + threadIdx.x;
    long stride = (long)gridDim.x * blockDim.x;
    for (; i < n4; i += stride) {
        int c4 = (int)(i & 31) * 4;
        float4 v = h[i];
        v.x = fmaxf(fmaf(v.x, s_ss[c4 + 0], s_ss[128 + c4 + 0]), 0.f);
        v.y = fmaxf(fmaf(v.y, s_ss[c4 + 1], s_ss[128 + c4 + 1]), 0.f);
        v.z = fmaxf(fmaf(v.z, s_ss[c4 + 2], s_ss[128 + c4 + 2]), 0.f);
        v.w = fmaxf(fmaf(v.w, s_ss[c4 + 3], s_ss[128 + c4 + 3]), 0.f);
        h[i] = v;
    }
}

static void run_layer(const float* in_feat, const int* ei, int Nn, int Ee,
                      const float* Wl, const float* bl, const float* Wr,
                      const float* gamma, const float* beta,
                      unsigned* agg, float* stats, float* ss,
                      float* out, hipStream_t stream) {
    long aggN = (long)Nn * 128;     // elements
    long n4 = aggN / 4;             // uint4 / float4 elements

    int initBlocks = (int)((n4 + 255) / 256);
    if (initBlocks > 4096) initBlocks = 4096;
    init_kernel<<<initBlocks, 256, 0, stream>>>((uint4*)agg, stats, n4);

    int sb = (int)(((long)Ee * 32 + 255) / 256);
    scatter_max_kernel<<<sb, 256, 0, stream>>>((const float4*)in_feat, ei, agg, Ee);

    gemm_kernel<<<(Nn + 63) / 64, 256, 0, stream>>>(agg, in_feat, Wl, Wr, bl, out, Nn);

    stats_kernel<<<512, 256, 0, stream>>>(out, stats, Nn);
    finalize_kernel<<<1, 128, 0, stream>>>(stats, gamma, beta, ss, 1.0f / (float)Nn);

    int bnBlocks = (int)((n4 + 255) / 256);
    if (bnBlocks > 8192) bnBlocks = 8192;
    bn_relu_kernel<<<bnBlocks, 256, 0, stream>>>((float4*)out, ss, n4);
}

extern "C" void kernel_launch(void* const* d_in, const int* in_sizes, int n_in,
                              void* d_out, int out_size, void* d_ws, size_t ws_size,
                              hipStream_t stream) {
    (void)n_in; (void)out_size; (void)ws_size;
    const float* x     = (const float*)d_in[0];
    const int*   ei    = (const int*)d_in[1];
    const float* W0_l  = (const float*)d_in[2];
    const float* b0_l  = (const float*)d_in[3];
    const float* W0_r  = (const float*)d_in[4];
    const float* g0    = (const float*)d_in[5];
    const float* be0   = (const float*)d_in[6];
    const float* W1_l  = (const float*)d_in[7];
    const float* b1_l  = (const float*)d_in[8];
    const float* W1_r  = (const float*)d_in[9];
    const float* g1    = (const float*)d_in[10];
    const float* be1   = (const float*)d_in[11];

    int Nn = in_sizes[0] / 128;
    int Ee = in_sizes[1] / 2;

    unsigned* agg  = (unsigned*)d_ws;
    float* stats   = (float*)((char*)d_ws + (size_t)Nn * 128 * sizeof(unsigned));
    float* ss      = stats + 256;
    float* out     = (float*)d_out;

    // layer 0: x -> out (h0, then BN+ReLU in place -> y0)
    run_layer(x, ei, Nn, Ee, W0_l, b0_l, W0_r, g0, be0, agg, stats, ss, out, stream);
    // layer 1: y0 (=out) -> out in place (GEMM blocks only touch their own rows)
    run_layer(out, ei, Nn, Ee, W1_l, b1_l, W1_r, g1, be1, agg, stats, ss, out, stream);
}

// Round 2
// 971.254 us; speedup vs baseline: 4.6349x; 4.6349x over previous
//
#include <hip/hip_runtime.h>
#include <stdint.h>

#define EPS_BN 1e-5f

// ============================================================================
// CSR build (done once; edge_index is shared by both layers)
// ============================================================================

extern "C" __global__ __launch_bounds__(256)
void zero_int_kernel(int* __restrict__ p, int n) {
    int i = blockIdx.x * 256 + threadIdx.x;
    if (i < n) p[i] = 0;
}

extern "C" __global__ __launch_bounds__(256)
void hist_kernel(const int* __restrict__ ei, int* __restrict__ deg, int E) {
    int e = blockIdx.x * 256 + threadIdx.x;
    if (e < E) atomicAdd(&deg[ei[E + e]], 1);
}

// single-block exclusive scan over deg[0..Nn) -> row_start[0..Nn], cursor copy
extern "C" __global__ __launch_bounds__(1024)
void scan_kernel(const int* __restrict__ deg, int* __restrict__ row_start,
                 int* __restrict__ cursor, int Nn) {
    __shared__ int partial[1024];
    int t = threadIdx.x;
    int chunk = (Nn + 1023) >> 10;
    int lo = t * chunk;
    int hi = lo + chunk;
    if (lo > Nn) lo = Nn;
    if (hi > Nn) hi = Nn;
    int s = 0;
    for (int i = lo; i < hi; ++i) s += deg[i];
    partial[t] = s;
    __syncthreads();
    for (int off = 1; off < 1024; off <<= 1) {
        int add = (t >= off) ? partial[t - off] : 0;   // prev iter ended in sync
        __syncthreads();
        partial[t] += add;
        __syncthreads();
    }
    int run = (t == 0) ? 0 : partial[t - 1];
    for (int i = lo; i < hi; ++i) {
        int d = deg[i];
        row_start[i] = run;
        cursor[i] = run;
        run += d;
    }
    if (t == 1023) row_start[Nn] = run;
}

extern "C" __global__ __launch_bounds__(256)
void scatter_edges_kernel(const int* __restrict__ ei, int* __restrict__ cursor,
                          int* __restrict__ ssrc, int E) {
    int e = blockIdx.x * 256 + threadIdx.x;
    if (e < E) {
        int pos = atomicAdd(&cursor[ei[E + e]], 1);
        ssrc[pos] = ei[e];
    }
}

// ============================================================================
// gather-max aggregation: 32 lanes per node, float4 per lane
// ============================================================================
extern "C" __global__ __launch_bounds__(256)
void gather_max_kernel(const float4* __restrict__ x, const int* __restrict__ row_start,
                       const int* __restrict__ ssrc, float4* __restrict__ agg, int Nn) {
    int t = blockIdx.x * 256 + threadIdx.x;
    int node = t >> 5;
    if (node >= Nn) return;
    int lane = t & 31;
    int beg = row_start[node];
    int end = row_start[node + 1];
    float4 acc;
    if (beg < end) {
        int s = ssrc[beg];
        acc = x[(size_t)s * 32 + lane];
        for (int e = beg + 1; e < end; ++e) {
            int s2 = ssrc[e];
            float4 v = x[(size_t)s2 * 32 + lane];
            acc.x = fmaxf(acc.x, v.x);
            acc.y = fmaxf(acc.y, v.y);
            acc.z = fmaxf(acc.z, v.z);
            acc.w = fmaxf(acc.w, v.w);
        }
    } else {
        acc.x = acc.y = acc.z = acc.w = 0.0f;   // PyG fills empty segments with 0
    }
    agg[(size_t)node * 32 + lane] = acc;
}

// ============================================================================
// fallback path (atomic scatter-max) — used only if ws_size is too small
// ============================================================================
__device__ __forceinline__ unsigned map_f(float f) {
    unsigned u = __float_as_uint(f);
    return (u & 0x80000000u) ? ~u : (u | 0x80000000u);
}
__device__ __forceinline__ float unmap_f(unsigned m) {
    return (m & 0x80000000u) ? __uint_as_float(m & 0x7FFFFFFFu) : __uint_as_float(~m);
}

extern "C" __global__ __launch_bounds__(256)
void init_sentinel_kernel(uint4* __restrict__ agg, long n4) {
    uint4 z = {0u, 0u, 0u, 0u};
    long i = (long)blockIdx.x * blockDim.x + threadIdx.x;
    long stride = (long)gridDim.x * blockDim.x;
    for (; i < n4; i += stride) agg[i] = z;
}

extern "C" __global__ __launch_bounds__(256)
void scatter_max_kernel(const float4* __restrict__ xin, const int* __restrict__ ei,
                        unsigned* __restrict__ agg, int E) {
    int t = blockIdx.x * 256 + threadIdx.x;
    int e = t >> 5;
    if (e >= E) return;
    int f4 = t & 31;
    int src = ei[e];
    int dst = ei[E + e];
    float4 v = xin[(size_t)src * 32 + f4];
    unsigned* p = agg + (size_t)dst * 128 + (size_t)f4 * 4;
    atomicMax(p + 0, map_f(v.x));
    atomicMax(p + 1, map_f(v.y));
    atomicMax(p + 2, map_f(v.z));
    atomicMax(p + 3, map_f(v.w));
}

extern "C" __global__ __launch_bounds__(256)
void unmap_kernel(unsigned* __restrict__ agg, long n) {
    long i = (long)blockIdx.x * blockDim.x + threadIdx.x;
    long stride = (long)gridDim.x * blockDim.x;
    for (; i < n; i += stride) {
        unsigned u = agg[i];
        agg[i] = __float_as_uint(u ? unmap_f(u) : 0.0f);
    }
}

// ============================================================================
// fused GEMM: h = agg @ Wl + bias + xin @ Wr      (agg now plain float)
// BM=64, BN=128, BK=32, 256 threads, 4x8 outputs/thread
// ============================================================================
extern "C" __global__ __launch_bounds__(256)
void gemm_kernel(const float* __restrict__ agg, const float* __restrict__ xin,
                 const float* __restrict__ Wl, const float* __restrict__ Wr,
                 const float* __restrict__ bias, float* __restrict__ h, int nrows) {
    __shared__ __align__(16) float As[64][36];
    __shared__ __align__(16) float Bs[32][136];

    const int t = threadIdx.x;
    const int tx = t & 15;
    const int ty = t >> 4;
    const int tx8 = tx * 8;
    const int ty4 = ty * 4;
    const int blockRow = blockIdx.x * 64;

    float acc[4][8];
#pragma unroll
    for (int j = 0; j < 4; ++j)
#pragma unroll
        for (int c = 0; c < 8; ++c) acc[j][c] = 0.0f;

    for (int kt = 0; kt < 8; ++kt) {
        const int k0 = kt * 32;
        const bool isAgg = (kt < 4);
        const float* W = isAgg ? Wl : Wr;
        const float* Asrc = isAgg ? agg : xin;
        const int kw = isAgg ? k0 : (k0 - 128);

#pragma unroll
        for (int it = 0; it < 4; ++it) {
            int idx = t + it * 256;
            int kr = idx >> 5, cq = idx & 31;
            float4 w = *(const float4*)&W[(size_t)(kw + kr) * 128 + cq * 4];
            *(float4*)&Bs[kr][cq * 4] = w;
        }
#pragma unroll
        for (int it = 0; it < 2; ++it) {
            int idx = t + it * 256;
            int r = idx >> 3, kq = idx & 7;
            int row_g = blockRow + r;
            float4 a = {0.f, 0.f, 0.f, 0.f};
            if (row_g < nrows)
                a = *(const float4*)&Asrc[(size_t)row_g * 128 + kw + kq * 4];
            *(float4*)&As[r][kq * 4] = a;
        }
        __syncthreads();

#pragma unroll
        for (int kk = 0; kk < 32; ++kk) {
            float aa[4];
            aa[0] = As[ty4 + 0][kk];
            aa[1] = As[ty4 + 1][kk];
            aa[2] = As[ty4 + 2][kk];
            aa[3] = As[ty4 + 3][kk];
            float4 b0 = *(const float4*)&Bs[kk][tx8];
            float4 b1 = *(const float4*)&Bs[kk][tx8 + 4];
            float bb[8] = {b0.x, b0.y, b0.z, b0.w, b1.x, b1.y, b1.z, b1.w};
#pragma unroll
            for (int j = 0; j < 4; ++j)
#pragma unroll
                for (int c = 0; c < 8; ++c)
                    acc[j][c] = fmaf(aa[j], bb[c], acc[j][c]);
        }
        __syncthreads();
    }

    float4 bv0 = *(const float4*)&bias[tx8];
    float4 bv1 = *(const float4*)&bias[tx8 + 4];
#pragma unroll
    for (int j = 0; j < 4; ++j) {
        int row = blockRow + ty4 + j;
        if (row < nrows) {
            float4 o0, o1;
            o0.x = acc[j][0] + bv0.x; o0.y = acc[j][1] + bv0.y;
            o0.z = acc[j][2] + bv0.z; o0.w = acc[j][3] + bv0.w;
            o1.x = acc[j][4] + bv1.x; o1.y = acc[j][5] + bv1.y;
            o1.z = acc[j][6] + bv1.z; o1.w = acc[j][7] + bv1.w;
            *(float4*)&h[(size_t)row * 128 + tx8] = o0;
            *(float4*)&h[(size_t)row * 128 + tx8 + 4] = o1;
        }
    }
}

// ============================================================================
// BatchNorm + ReLU
// ============================================================================
extern "C" __global__
void zero_stats_kernel(float* __restrict__ stats) {
    stats[threadIdx.x] = 0.0f;
}

extern "C" __global__ __launch_bounds__(256)
void stats_kernel(const float* __restrict__ h, float* __restrict__ stats, int nrows) {
    __shared__ float ssum[256];
    __shared__ float ssq[256];
    int t = threadIdx.x;
    int c = t & 127;
    int rhalf = t >> 7;
    float s = 0.f, q = 0.f;
    for (int r = blockIdx.x * 2 + rhalf; r < nrows; r += gridDim.x * 2) {
        float v = h[(size_t)r * 128 + c];
        s += v;
        q += v * v;
    }
    ssum[t] = s;
    ssq[t] = q;
    __syncthreads();
    if (t < 128) {
        atomicAdd(&stats[c], ssum[t] + ssum[t + 128]);
        atomicAdd(&stats[128 + c], ssq[t] + ssq[t + 128]);
    }
}

extern "C" __global__
void finalize_kernel(const float* __restrict__ stats, const float* __restrict__ gamma,
                     const float* __restrict__ beta, float* __restrict__ ss, float inv_n) {
    int c = threadIdx.x;
    if (c < 128) {
        float mu = stats[c] * inv_n;
        float var = stats[128 + c] * inv_n - mu * mu;
        float sc = gamma[c] * rsqrtf(var + EPS_BN);
        ss[c] = sc;
        ss[128 + c] = beta[c] - mu * sc;
    }
}

extern "C" __global__ __launch_bounds__(256)
void bn_relu_kernel(float4* __restrict__ h, const float* __restrict__ ss, long n4) {
    __shared__ float s_ss[256];
    if (threadIdx.x < 256) s_ss[threadIdx.x] = ss[threadIdx.x];
    __syncthreads();
    long i = (long)blockIdx.x * blockDim.x + threadIdx.x;
    long stride = (long)gridDim.x * blockDim.x;
    for (; i < n4; i += stride) {
        int c4 = (int)(i & 31) * 4;
        float4 v = h[i];
        v.x = fmaxf(fmaf(v.x, s_ss[c4 + 0], s_ss[128 + c4 + 0]), 0.f);
        v.y = fmaxf(fmaf(v.y, s_ss[c4 + 1], s_ss[128 + c4 + 1]), 0.f);
        v.z = fmaxf(fmaf(v.z, s_ss[c4 + 2], s_ss[128 + c4 + 2]), 0.f);
        v.w = fmaxf(fmaf(v.w, s_ss[c4 + 3], s_ss[128 + c4 + 3]), 0.f);
        h[i] = v;
    }
}

// ============================================================================
// host-side orchestration
// ============================================================================
static void run_layer_csr(const float* in_feat, const int* row_start, const int* ssrc,
                          int Nn, const float* Wl, const float* bl, const float* Wr,
                          const float* gamma, const float* beta,
                          float* agg, float* stats, float* ss,
                          float* out, hipStream_t stream) {
    long n4 = (long)Nn * 32;

    zero_stats_kernel<<<1, 256, 0, stream>>>(stats);
    gather_max_kernel<<<(Nn * 32 + 255) / 256, 256, 0, stream>>>(
        (const float4*)in_feat, row_start, ssrc, (float4*)agg, Nn);
    gemm_kernel<<<(Nn + 63) / 64, 256, 0, stream>>>(agg, in_feat, Wl, Wr, bl, out, Nn);
    stats_kernel<<<512, 256, 0, stream>>>(out, stats, Nn);
    finalize_kernel<<<1, 128, 0, stream>>>(stats, gamma, beta, ss, 1.0f / (float)Nn);
    int bnBlocks = (int)((n4 + 255) / 256);
    if (bnBlocks > 8192) bnBlocks = 8192;
    bn_relu_kernel<<<bnBlocks, 256, 0, stream>>>((float4*)out, ss, n4);
}

static void run_layer_atomic(const float* in_feat, const int* ei, int Nn, int Ee,
                             const float* Wl, const float* bl, const float* Wr,
                             const float* gamma, const float* beta,
                             float* agg, float* stats, float* ss,
                             float* out, hipStream_t stream) {
    long aggN = (long)Nn * 128;
    long n4 = aggN / 4;

    zero_stats_kernel<<<1, 256, 0, stream>>>(stats);
    int initBlocks = (int)((n4 + 255) / 256);
    if (initBlocks > 4096) initBlocks = 4096;
    init_sentinel_kernel<<<initBlocks, 256, 0, stream>>>((uint4*)agg, n4);
    int sb = (int)(((long)Ee * 32 + 255) / 256);
    scatter_max_kernel<<<sb, 256, 0, stream>>>((const float4*)in_feat, ei,
                                               (unsigned*)agg, Ee);
    int ub = (int)((aggN + 255) / 256);
    if (ub > 8192) ub = 8192;
    unmap_kernel<<<ub, 256, 0, stream>>>((unsigned*)agg, aggN);
    gemm_kernel<<<(Nn + 63) / 64, 256, 0, stream>>>(agg, in_feat, Wl, Wr, bl, out, Nn);
    stats_kernel<<<512, 256, 0, stream>>>(out, stats, Nn);
    finalize_kernel<<<1, 128, 0, stream>>>(stats, gamma, beta, ss, 1.0f / (float)Nn);
    int bnBlocks = (int)((n4 + 255) / 256);
    if (bnBlocks > 8192) bnBlocks = 8192;
    bn_relu_kernel<<<bnBlocks, 256, 0, stream>>>((float4*)out, ss, n4);
}

extern "C" void kernel_launch(void* const* d_in, const int* in_sizes, int n_in,
                              void* d_out, int out_size, void* d_ws, size_t ws_size,
                              hipStream_t stream) {
    (void)n_in; (void)out_size;
    const float* x     = (const float*)d_in[0];
    const int*   ei    = (const int*)d_in[1];
    const float* W0_l  = (const float*)d_in[2];
    const float* b0_l  = (const float*)d_in[3];
    const float* W0_r  = (const float*)d_in[4];
    const float* g0    = (const float*)d_in[5];
    const float* be0   = (const float*)d_in[6];
    const float* W1_l  = (const float*)d_in[7];
    const float* b1_l  = (const float*)d_in[8];
    const float* W1_r  = (const float*)d_in[9];
    const float* g1    = (const float*)d_in[10];
    const float* be1   = (const float*)d_in[11];

    int Nn = in_sizes[0] / 128;
    int Ee = in_sizes[1] / 2;

    size_t aggBytes = (size_t)Nn * 128 * sizeof(float);
    char* p = (char*)d_ws;
    float* agg = (float*)p;              p += aggBytes;
    float* stats = (float*)p;            p += 256 * sizeof(float);
    float* ss = (float*)p;               p += 256 * sizeof(float);
    int* deg = (int*)p;                  p += (size_t)Nn * sizeof(int);
    int* row_start = (int*)p;            p += (size_t)(Nn + 1) * sizeof(int);
    int* cursor = (int*)p;               p += (size_t)Nn * sizeof(int);
    int* ssrc = (int*)p;                 p += (size_t)Ee * sizeof(int);
    size_t needed = (size_t)(p - (char*)d_ws);
    float* out = (float*)d_out;

    if (ws_size >= needed) {
        // ---- CSR path ----
        zero_int_kernel<<<(Nn + 255) / 256, 256, 0, stream>>>(deg, Nn);
        hist_kernel<<<(Ee + 255) / 256, 256, 0, stream>>>(ei, deg, Ee);
        scan_kernel<<<1, 1024, 0, stream>>>(deg, row_start, cursor, Nn);
        scatter_edges_kernel<<<(Ee + 255) / 256, 256, 0, stream>>>(ei, cursor, ssrc, Ee);

        run_layer_csr(x, row_start, ssrc, Nn, W0_l, b0_l, W0_r, g0, be0,
                      agg, stats, ss, out, stream);
        run_layer_csr(out, row_start, ssrc, Nn, W1_l, b1_l, W1_r, g1, be1,
                      agg, stats, ss, out, stream);
    } else {
        // ---- fallback: atomic path ----
        run_layer_atomic(x, ei, Nn, Ee, W0_l, b0_l, W0_r, g0, be0,
                         agg, stats, ss, out, stream);
        run_layer_atomic(out, ei, Nn, Ee, W1_l, b1_l, W1_r, g1, be1,
                         agg, stats, ss, out, stream);
    }
}

// Round 3
// 739.094 us; speedup vs baseline: 6.0908x; 1.3141x over previous
//
#include <hip/hip_runtime.h>
#include <stdint.h>

#define EPS_BN 1e-5f

// ============================================================================
// CSR build (done once; edge_index is shared by both layers)
// ============================================================================

extern "C" __global__ __launch_bounds__(256)
void zero_int_kernel(int* __restrict__ p, int n) {
    int i = blockIdx.x * 256 + threadIdx.x;
    if (i < n) p[i] = 0;
}

extern "C" __global__ __launch_bounds__(256)
void hist_kernel(const int* __restrict__ ei, int* __restrict__ deg, int E) {
    int e = blockIdx.x * 256 + threadIdx.x;
    if (e < E) atomicAdd(&deg[ei[E + e]], 1);
}

// ---- device-wide exclusive scan, 3 kernels, 1024 elements per block ---------
// A: per-block sums
extern "C" __global__ __launch_bounds__(256)
void block_sum_kernel(const int* __restrict__ deg, int* __restrict__ bsum, int Nn) {
    __shared__ int tsum[256];
    int t = threadIdx.x;
    int base = blockIdx.x * 1024 + t * 4;
    int s = 0;
#pragma unroll
    for (int j = 0; j < 4; ++j) {
        int i = base + j;
        if (i < Nn) s += deg[i];
    }
    tsum[t] = s;
    __syncthreads();
    for (int off = 128; off > 0; off >>= 1) {
        if (t < off) tsum[t] += tsum[t + off];
        __syncthreads();
    }
    if (t == 0) bsum[blockIdx.x] = tsum[0];
}

// B: single-block exclusive scan of block sums (NB <= 1024)
extern "C" __global__ __launch_bounds__(1024)
void scan_bsums_kernel(const int* __restrict__ bsum, int* __restrict__ boff, int NB) {
    __shared__ int sh[1024];
    int t = threadIdx.x;
    int v = (t < NB) ? bsum[t] : 0;
    sh[t] = v;
    __syncthreads();
    for (int off = 1; off < 1024; off <<= 1) {
        int add = (t >= off) ? sh[t - off] : 0;
        __syncthreads();
        sh[t] += add;
        __syncthreads();
    }
    if (t < NB) boff[t] = sh[t] - v;   // exclusive
}

// C: block-local scan + offset, write row_start and cursor
extern "C" __global__ __launch_bounds__(256)
void scan_apply_kernel(const int* __restrict__ deg, const int* __restrict__ boff,
                       int* __restrict__ row_start, int* __restrict__ cursor, int Nn) {
    __shared__ int tsum[256];
    int t = threadIdx.x;
    int base = blockIdx.x * 1024 + t * 4;
    int v[4];
    int s = 0;
#pragma unroll
    for (int j = 0; j < 4; ++j) {
        int i = base + j;
        v[j] = (i < Nn) ? deg[i] : 0;
        s += v[j];
    }
    tsum[t] = s;
    __syncthreads();
    for (int off = 1; off < 256; off <<= 1) {
        int add = (t >= off) ? tsum[t - off] : 0;
        __syncthreads();
        tsum[t] += add;
        __syncthreads();
    }
    int run = boff[blockIdx.x] + (t ? tsum[t - 1] : 0);
#pragma unroll
    for (int j = 0; j < 4; ++j) {
        int i = base + j;
        if (i < Nn) {
            row_start[i] = run;
            cursor[i] = run;
            run += v[j];
        }
    }
    if (blockIdx.x == gridDim.x - 1 && t == 255)
        row_start[Nn] = boff[blockIdx.x] + tsum[255];
}

extern "C" __global__ __launch_bounds__(256)
void scatter_edges_kernel(const int* __restrict__ ei, int* __restrict__ cursor,
                          int* __restrict__ ssrc, int E) {
    int e = blockIdx.x * 256 + threadIdx.x;
    if (e < E) {
        int pos = atomicAdd(&cursor[ei[E + e]], 1);
        ssrc[pos] = ei[e];
    }
}

// ============================================================================
// gather-max aggregation: 32 lanes per node, float4 per lane, 2-way unroll
// ============================================================================
extern "C" __global__ __launch_bounds__(256)
void gather_max_kernel(const float4* __restrict__ x, const int* __restrict__ row_start,
                       const int* __restrict__ ssrc, float4* __restrict__ agg, int Nn) {
    int t = blockIdx.x * 256 + threadIdx.x;
    int node = t >> 5;
    if (node >= Nn) return;
    int lane = t & 31;
    int beg = row_start[node];
    int end = row_start[node + 1];
    float4 acc;
    if (beg < end) {
        int s0 = ssrc[beg];
        acc = x[(size_t)s0 * 32 + lane];
        int e = beg + 1;
        if (((end - beg) & 1) == 0) {           // consume one to make remainder even
            int s = ssrc[e];
            float4 v = x[(size_t)s * 32 + lane];
            acc.x = fmaxf(acc.x, v.x); acc.y = fmaxf(acc.y, v.y);
            acc.z = fmaxf(acc.z, v.z); acc.w = fmaxf(acc.w, v.w);
            ++e;
        }
        for (; e < end; e += 2) {
            int sa = ssrc[e];
            int sb = ssrc[e + 1];
            float4 va = x[(size_t)sa * 32 + lane];
            float4 vb = x[(size_t)sb * 32 + lane];
            va.x = fmaxf(va.x, vb.x); va.y = fmaxf(va.y, vb.y);
            va.z = fmaxf(va.z, vb.z); va.w = fmaxf(va.w, vb.w);
            acc.x = fmaxf(acc.x, va.x); acc.y = fmaxf(acc.y, va.y);
            acc.z = fmaxf(acc.z, va.z); acc.w = fmaxf(acc.w, va.w);
        }
    } else {
        acc.x = acc.y = acc.z = acc.w = 0.0f;   // PyG fills empty segments with 0
    }
    agg[(size_t)node * 32 + lane] = acc;
}

// ============================================================================
// fallback path (atomic scatter-max) — used only if ws_size is too small
// ============================================================================
__device__ __forceinline__ unsigned map_f(float f) {
    unsigned u = __float_as_uint(f);
    return (u & 0x80000000u) ? ~u : (u | 0x80000000u);
}
__device__ __forceinline__ float unmap_f(unsigned m) {
    return (m & 0x80000000u) ? __uint_as_float(m & 0x7FFFFFFFu) : __uint_as_float(~m);
}

extern "C" __global__ __launch_bounds__(256)
void init_sentinel_kernel(uint4* __restrict__ agg, long n4) {
    uint4 z = {0u, 0u, 0u, 0u};
    long i = (long)blockIdx.x * blockDim.x + threadIdx.x;
    long stride = (long)gridDim.x * blockDim.x;
    for (; i < n4; i += stride) agg[i] = z;
}

extern "C" __global__ __launch_bounds__(256)
void scatter_max_kernel(const float4* __restrict__ xin, const int* __restrict__ ei,
                        unsigned* __restrict__ agg, int E) {
    int t = blockIdx.x * 256 + threadIdx.x;
    int e = t >> 5;
    if (e >= E) return;
    int f4 = t & 31;
    int src = ei[e];
    int dst = ei[E + e];
    float4 v = xin[(size_t)src * 32 + f4];
    unsigned* p = agg + (size_t)dst * 128 + (size_t)f4 * 4;
    atomicMax(p + 0, map_f(v.x));
    atomicMax(p + 1, map_f(v.y));
    atomicMax(p + 2, map_f(v.z));
    atomicMax(p + 3, map_f(v.w));
}

extern "C" __global__ __launch_bounds__(256)
void unmap_kernel(unsigned* __restrict__ agg, long n) {
    long i = (long)blockIdx.x * blockDim.x + threadIdx.x;
    long stride = (long)gridDim.x * blockDim.x;
    for (; i < n; i += stride) {
        unsigned u = agg[i];
        agg[i] = __float_as_uint(u ? unmap_f(u) : 0.0f);
    }
}

// ============================================================================
// fused GEMM: h = agg @ Wl + bias + xin @ Wr
// BM=64, BN=128, BK=32, 256 threads, 4x8 outputs/thread
// ============================================================================
extern "C" __global__ __launch_bounds__(256)
void gemm_kernel(const float* __restrict__ agg, const float* __restrict__ xin,
                 const float* __restrict__ Wl, const float* __restrict__ Wr,
                 const float* __restrict__ bias, float* __restrict__ h, int nrows) {
    __shared__ __align__(16) float As[64][36];
    __shared__ __align__(16) float Bs[32][136];

    const int t = threadIdx.x;
    const int tx = t & 15;
    const int ty = t >> 4;
    const int tx8 = tx * 8;
    const int ty4 = ty * 4;
    const int blockRow = blockIdx.x * 64;

    float acc[4][8];
#pragma unroll
    for (int j = 0; j < 4; ++j)
#pragma unroll
        for (int c = 0; c < 8; ++c) acc[j][c] = 0.0f;

    for (int kt = 0; kt < 8; ++kt) {
        const int k0 = kt * 32;
        const bool isAgg = (kt < 4);
        const float* W = isAgg ? Wl : Wr;
        const float* Asrc = isAgg ? agg : xin;
        const int kw = isAgg ? k0 : (k0 - 128);

#pragma unroll
        for (int it = 0; it < 4; ++it) {
            int idx = t + it * 256;
            int kr = idx >> 5, cq = idx & 31;
            float4 w = *(const float4*)&W[(size_t)(kw + kr) * 128 + cq * 4];
            *(float4*)&Bs[kr][cq * 4] = w;
        }
#pragma unroll
        for (int it = 0; it < 2; ++it) {
            int idx = t + it * 256;
            int r = idx >> 3, kq = idx & 7;
            int row_g = blockRow + r;
            float4 a = {0.f, 0.f, 0.f, 0.f};
            if (row_g < nrows)
                a = *(const float4*)&Asrc[(size_t)row_g * 128 + kw + kq * 4];
            *(float4*)&As[r][kq * 4] = a;
        }
        __syncthreads();

#pragma unroll
        for (int kk = 0; kk < 32; ++kk) {
            float aa[4];
            aa[0] = As[ty4 + 0][kk];
            aa[1] = As[ty4 + 1][kk];
            aa[2] = As[ty4 + 2][kk];
            aa[3] = As[ty4 + 3][kk];
            float4 b0 = *(const float4*)&Bs[kk][tx8];
            float4 b1 = *(const float4*)&Bs[kk][tx8 + 4];
            float bb[8] = {b0.x, b0.y, b0.z, b0.w, b1.x, b1.y, b1.z, b1.w};
#pragma unroll
            for (int j = 0; j < 4; ++j)
#pragma unroll
                for (int c = 0; c < 8; ++c)
                    acc[j][c] = fmaf(aa[j], bb[c], acc[j][c]);
        }
        __syncthreads();
    }

    float4 bv0 = *(const float4*)&bias[tx8];
    float4 bv1 = *(const float4*)&bias[tx8 + 4];
#pragma unroll
    for (int j = 0; j < 4; ++j) {
        int row = blockRow + ty4 + j;
        if (row < nrows) {
            float4 o0, o1;
            o0.x = acc[j][0] + bv0.x; o0.y = acc[j][1] + bv0.y;
            o0.z = acc[j][2] + bv0.z; o0.w = acc[j][3] + bv0.w;
            o1.x = acc[j][4] + bv1.x; o1.y = acc[j][5] + bv1.y;
            o1.z = acc[j][6] + bv1.z; o1.w = acc[j][7] + bv1.w;
            *(float4*)&h[(size_t)row * 128 + tx8] = o0;
            *(float4*)&h[(size_t)row * 128 + tx8 + 4] = o1;
        }
    }
}

// ============================================================================
// BatchNorm + ReLU
// ============================================================================
extern "C" __global__
void zero_stats_kernel(float* __restrict__ stats) {
    stats[threadIdx.x] = 0.0f;
}

extern "C" __global__ __launch_bounds__(256)
void stats_kernel(const float* __restrict__ h, float* __restrict__ stats, int nrows) {
    __shared__ float ssum[256];
    __shared__ float ssq[256];
    int t = threadIdx.x;
    int c = t & 127;
    int rhalf = t >> 7;
    float s = 0.f, q = 0.f;
    for (int r = blockIdx.x * 2 + rhalf; r < nrows; r += gridDim.x * 2) {
        float v = h[(size_t)r * 128 + c];
        s += v;
        q += v * v;
    }
    ssum[t] = s;
    ssq[t] = q;
    __syncthreads();
    if (t < 128) {
        atomicAdd(&stats[c], ssum[t] + ssum[t + 128]);
        atomicAdd(&stats[128 + c], ssq[t] + ssq[t + 128]);
    }
}

extern "C" __global__
void finalize_kernel(const float* __restrict__ stats, const float* __restrict__ gamma,
                     const float* __restrict__ beta, float* __restrict__ ss, float inv_n) {
    int c = threadIdx.x;
    if (c < 128) {
        float mu = stats[c] * inv_n;
        float var = stats[128 + c] * inv_n - mu * mu;
        float sc = gamma[c] * rsqrtf(var + EPS_BN);
        ss[c] = sc;
        ss[128 + c] = beta[c] - mu * sc;
    }
}

extern "C" __global__ __launch_bounds__(256)
void bn_relu_kernel(float4* __restrict__ h, const float* __restrict__ ss, long n4) {
    __shared__ float s_ss[256];
    if (threadIdx.x < 256) s_ss[threadIdx.x] = ss[threadIdx.x];
    __syncthreads();
    long i = (long)blockIdx.x * blockDim.x + threadIdx.x;
    long stride = (long)gridDim.x * blockDim.x;
    for (; i < n4; i += stride) {
        int c4 = (int)(i & 31) * 4;
        float4 v = h[i];
        v.x = fmaxf(fmaf(v.x, s_ss[c4 + 0], s_ss[128 + c4 + 0]), 0.f);
        v.y = fmaxf(fmaf(v.y, s_ss[c4 + 1], s_ss[128 + c4 + 1]), 0.f);
        v.z = fmaxf(fmaf(v.z, s_ss[c4 + 2], s_ss[128 + c4 + 2]), 0.f);
        v.w = fmaxf(fmaf(v.w, s_ss[c4 + 3], s_ss[128 + c4 + 3]), 0.f);
        h[i] = v;
    }
}

// ============================================================================
// host-side orchestration
// ============================================================================
static void run_layer_csr(const float* in_feat, const int* row_start, const int* ssrc,
                          int Nn, const float* Wl, const float* bl, const float* Wr,
                          const float* gamma, const float* beta,
                          float* agg, float* stats, float* ss,
                          float* out, hipStream_t stream) {
    long n4 = (long)Nn * 32;

    zero_stats_kernel<<<1, 256, 0, stream>>>(stats);
    gather_max_kernel<<<(Nn * 32 + 255) / 256, 256, 0, stream>>>(
        (const float4*)in_feat, row_start, ssrc, (float4*)agg, Nn);
    gemm_kernel<<<(Nn + 63) / 64, 256, 0, stream>>>(agg, in_feat, Wl, Wr, bl, out, Nn);
    stats_kernel<<<512, 256, 0, stream>>>(out, stats, Nn);
    finalize_kernel<<<1, 128, 0, stream>>>(stats, gamma, beta, ss, 1.0f / (float)Nn);
    int bnBlocks = (int)((n4 + 255) / 256);
    if (bnBlocks > 8192) bnBlocks = 8192;
    bn_relu_kernel<<<bnBlocks, 256, 0, stream>>>((float4*)out, ss, n4);
}

static void run_layer_atomic(const float* in_feat, const int* ei, int Nn, int Ee,
                             const float* Wl, const float* bl, const float* Wr,
                             const float* gamma, const float* beta,
                             float* agg, float* stats, float* ss,
                             float* out, hipStream_t stream) {
    long aggN = (long)Nn * 128;
    long n4 = aggN / 4;

    zero_stats_kernel<<<1, 256, 0, stream>>>(stats);
    int initBlocks = (int)((n4 + 255) / 256);
    if (initBlocks > 4096) initBlocks = 4096;
    init_sentinel_kernel<<<initBlocks, 256, 0, stream>>>((uint4*)agg, n4);
    int sb = (int)(((long)Ee * 32 + 255) / 256);
    scatter_max_kernel<<<sb, 256, 0, stream>>>((const float4*)in_feat, ei,
                                               (unsigned*)agg, Ee);
    int ub = (int)((aggN + 255) / 256);
    if (ub > 8192) ub = 8192;
    unmap_kernel<<<ub, 256, 0, stream>>>((unsigned*)agg, aggN);
    gemm_kernel<<<(Nn + 63) / 64, 256, 0, stream>>>(agg, in_feat, Wl, Wr, bl, out, Nn);
    stats_kernel<<<512, 256, 0, stream>>>(out, stats, Nn);
    finalize_kernel<<<1, 128, 0, stream>>>(stats, gamma, beta, ss, 1.0f / (float)Nn);
    int bnBlocks = (int)((n4 + 255) / 256);
    if (bnBlocks > 8192) bnBlocks = 8192;
    bn_relu_kernel<<<bnBlocks, 256, 0, stream>>>((float4*)out, ss, n4);
}

extern "C" void kernel_launch(void* const* d_in, const int* in_sizes, int n_in,
                              void* d_out, int out_size, void* d_ws, size_t ws_size,
                              hipStream_t stream) {
    (void)n_in; (void)out_size;
    const float* x     = (const float*)d_in[0];
    const int*   ei    = (const int*)d_in[1];
    const float* W0_l  = (const float*)d_in[2];
    const float* b0_l  = (const float*)d_in[3];
    const float* W0_r  = (const float*)d_in[4];
    const float* g0    = (const float*)d_in[5];
    const float* be0   = (const float*)d_in[6];
    const float* W1_l  = (const float*)d_in[7];
    const float* b1_l  = (const float*)d_in[8];
    const float* W1_r  = (const float*)d_in[9];
    const float* g1    = (const float*)d_in[10];
    const float* be1   = (const float*)d_in[11];

    int Nn = in_sizes[0] / 128;
    int Ee = in_sizes[1] / 2;

    int NB = (Nn + 1023) / 1024;           // blocks for the device-wide scan

    size_t aggBytes = (size_t)Nn * 128 * sizeof(float);
    char* p = (char*)d_ws;
    float* agg = (float*)p;              p += aggBytes;
    float* stats = (float*)p;            p += 256 * sizeof(float);
    float* ss = (float*)p;               p += 256 * sizeof(float);
    int* deg = (int*)p;                  p += (size_t)Nn * sizeof(int);
    int* row_start = (int*)p;            p += (size_t)(Nn + 1) * sizeof(int);
    int* cursor = (int*)p;               p += (size_t)Nn * sizeof(int);
    int* bsum = (int*)p;                 p += (size_t)NB * sizeof(int);
    int* boff = (int*)p;                 p += (size_t)NB * sizeof(int);
    int* ssrc = (int*)p;                 p += (size_t)Ee * sizeof(int);
    size_t needed = (size_t)(p - (char*)d_ws);
    float* out = (float*)d_out;

    if (ws_size >= needed && NB <= 1024) {
        // ---- CSR path ----
        zero_int_kernel<<<(Nn + 255) / 256, 256, 0, stream>>>(deg, Nn);
        hist_kernel<<<(Ee + 255) / 256, 256, 0, stream>>>(ei, deg, Ee);
        block_sum_kernel<<<NB, 256, 0, stream>>>(deg, bsum, Nn);
        scan_bsums_kernel<<<1, 1024, 0, stream>>>(bsum, boff, NB);
        scan_apply_kernel<<<NB, 256, 0, stream>>>(deg, boff, row_start, cursor, Nn);
        scatter_edges_kernel<<<(Ee + 255) / 256, 256, 0, stream>>>(ei, cursor, ssrc, Ee);

        run_layer_csr(x, row_start, ssrc, Nn, W0_l, b0_l, W0_r, g0, be0,
                      agg, stats, ss, out, stream);
        run_layer_csr(out, row_start, ssrc, Nn, W1_l, b1_l, W1_r, g1, be1,
                      agg, stats, ss, out, stream);
    } else {
        // ---- fallback: atomic path ----
        run_layer_atomic(x, ei, Nn, Ee, W0_l, b0_l, W0_r, g0, be0,
                         agg, stats, ss, out, stream);
        run_layer_atomic(out, ei, Nn, Ee, W1_l, b1_l, W1_r, g1, be1,
                         agg, stats, ss, out, stream);
    }
}

// Round 4
// 655.222 us; speedup vs baseline: 6.8704x; 1.1280x over previous
//
#include <hip/hip_runtime.h>
#include <stdint.h>

#define EPS_BN 1e-5f

// ============================================================================
// linked-list "CSR" build (once; edge_index shared by both layers)
//   head[dst] -> most recent edge id, next[e] -> previous edge with same dst
//   max-aggregation is order-independent, so list order doesn't matter.
// ============================================================================

extern "C" __global__ __launch_bounds__(256)
void init_head_kernel(int* __restrict__ head, int n) {
    int i = blockIdx.x * 256 + threadIdx.x;
    if (i < n) head[i] = -1;
}

extern "C" __global__ __launch_bounds__(256)
void link_kernel(const int* __restrict__ ei, int* __restrict__ head,
                 int* __restrict__ next, int E) {
    int e = blockIdx.x * 256 + threadIdx.x;
    if (e < E) {
        int dst = ei[E + e];
        int old = atomicExch(&head[dst], e);
        next[e] = old;               // coalesced sequential write
    }
}

// ============================================================================
// gather-max via list chase: 32 lanes per node, float4 per lane
// ============================================================================
extern "C" __global__ __launch_bounds__(256)
void gather_max_ll_kernel(const float4* __restrict__ x, const int* __restrict__ head,
                          const int* __restrict__ next, const int* __restrict__ ei,
                          float4* __restrict__ agg, int Nn) {
    int t = blockIdx.x * 256 + threadIdx.x;
    int node = t >> 5;
    if (node >= Nn) return;
    int lane = t & 31;
    int e = head[node];                       // uniform across the 32-lane group
    float4 acc;
    if (e >= 0) {
        int src = ei[e];
        int en = next[e];
        acc = x[(size_t)src * 32 + lane];
        while (en >= 0) {
            int s2 = ei[en];                  // independent of chase
            int en2 = next[en];               // chase
            float4 v = x[(size_t)s2 * 32 + lane];
            en = en2;
            acc.x = fmaxf(acc.x, v.x);
            acc.y = fmaxf(acc.y, v.y);
            acc.z = fmaxf(acc.z, v.z);
            acc.w = fmaxf(acc.w, v.w);
        }
    } else {
        acc.x = acc.y = acc.z = acc.w = 0.0f; // PyG fills empty segments with 0
    }
    agg[(size_t)node * 32 + lane] = acc;
}

// ============================================================================
// fallback path (atomic scatter-max) — used only if ws_size is too small
// ============================================================================
__device__ __forceinline__ unsigned map_f(float f) {
    unsigned u = __float_as_uint(f);
    return (u & 0x80000000u) ? ~u : (u | 0x80000000u);
}
__device__ __forceinline__ float unmap_f(unsigned m) {
    return (m & 0x80000000u) ? __uint_as_float(m & 0x7FFFFFFFu) : __uint_as_float(~m);
}

extern "C" __global__ __launch_bounds__(256)
void init_sentinel_kernel(uint4* __restrict__ agg, long n4) {
    uint4 z = {0u, 0u, 0u, 0u};
    long i = (long)blockIdx.x * blockDim.x + threadIdx.x;
    long stride = (long)gridDim.x * blockDim.x;
    for (; i < n4; i += stride) agg[i] = z;
}

extern "C" __global__ __launch_bounds__(256)
void scatter_max_kernel(const float4* __restrict__ xin, const int* __restrict__ ei,
                        unsigned* __restrict__ agg, int E) {
    int t = blockIdx.x * 256 + threadIdx.x;
    int e = t >> 5;
    if (e >= E) return;
    int f4 = t & 31;
    int src = ei[e];
    int dst = ei[E + e];
    float4 v = xin[(size_t)src * 32 + f4];
    unsigned* p = agg + (size_t)dst * 128 + (size_t)f4 * 4;
    atomicMax(p + 0, map_f(v.x));
    atomicMax(p + 1, map_f(v.y));
    atomicMax(p + 2, map_f(v.z));
    atomicMax(p + 3, map_f(v.w));
}

extern "C" __global__ __launch_bounds__(256)
void unmap_kernel(unsigned* __restrict__ agg, long n) {
    long i = (long)blockIdx.x * blockDim.x + threadIdx.x;
    long stride = (long)gridDim.x * blockDim.x;
    for (; i < n; i += stride) {
        unsigned u = agg[i];
        agg[i] = __float_as_uint(u ? unmap_f(u) : 0.0f);
    }
}

// ============================================================================
// fused GEMM + BN-stats: h = agg @ Wl + bias + xin @ Wr, stats += colsum/sumsq
// BM=64, BN=128, BK=32, 256 threads, 4x8 outputs/thread
// ============================================================================
extern "C" __global__ __launch_bounds__(256)
void gemm_kernel(const float* __restrict__ agg, const float* __restrict__ xin,
                 const float* __restrict__ Wl, const float* __restrict__ Wr,
                 const float* __restrict__ bias, float* __restrict__ h,
                 float* __restrict__ stats, int nrows) {
    __shared__ __align__(16) float As[64][36];
    __shared__ __align__(16) float Bs[32][136];
    __shared__ float redS[4][128];
    __shared__ float redQ[4][128];

    const int t = threadIdx.x;
    const int tx = t & 15;
    const int ty = t >> 4;
    const int tx8 = tx * 8;
    const int ty4 = ty * 4;
    const int blockRow = blockIdx.x * 64;

    float acc[4][8];
#pragma unroll
    for (int j = 0; j < 4; ++j)
#pragma unroll
        for (int c = 0; c < 8; ++c) acc[j][c] = 0.0f;

    for (int kt = 0; kt < 8; ++kt) {
        const int k0 = kt * 32;
        const bool isAgg = (kt < 4);
        const float* W = isAgg ? Wl : Wr;
        const float* Asrc = isAgg ? agg : xin;
        const int kw = isAgg ? k0 : (k0 - 128);

#pragma unroll
        for (int it = 0; it < 4; ++it) {
            int idx = t + it * 256;
            int kr = idx >> 5, cq = idx & 31;
            float4 w = *(const float4*)&W[(size_t)(kw + kr) * 128 + cq * 4];
            *(float4*)&Bs[kr][cq * 4] = w;
        }
#pragma unroll
        for (int it = 0; it < 2; ++it) {
            int idx = t + it * 256;
            int r = idx >> 3, kq = idx & 7;
            int row_g = blockRow + r;
            float4 a = {0.f, 0.f, 0.f, 0.f};
            if (row_g < nrows)
                a = *(const float4*)&Asrc[(size_t)row_g * 128 + kw + kq * 4];
            *(float4*)&As[r][kq * 4] = a;
        }
        __syncthreads();

#pragma unroll
        for (int kk = 0; kk < 32; ++kk) {
            float aa[4];
            aa[0] = As[ty4 + 0][kk];
            aa[1] = As[ty4 + 1][kk];
            aa[2] = As[ty4 + 2][kk];
            aa[3] = As[ty4 + 3][kk];
            float4 b0 = *(const float4*)&Bs[kk][tx8];
            float4 b1 = *(const float4*)&Bs[kk][tx8 + 4];
            float bb[8] = {b0.x, b0.y, b0.z, b0.w, b1.x, b1.y, b1.z, b1.w};
#pragma unroll
            for (int j = 0; j < 4; ++j)
#pragma unroll
                for (int c = 0; c < 8; ++c)
                    acc[j][c] = fmaf(aa[j], bb[c], acc[j][c]);
        }
        __syncthreads();
    }

    float bv[8];
#pragma unroll
    for (int c = 0; c < 8; ++c) bv[c] = bias[tx8 + c];

    float s_loc[8], q_loc[8];
#pragma unroll
    for (int c = 0; c < 8; ++c) { s_loc[c] = 0.f; q_loc[c] = 0.f; }

#pragma unroll
    for (int j = 0; j < 4; ++j) {
        int row = blockRow + ty4 + j;
        if (row < nrows) {
            float o[8];
#pragma unroll
            for (int c = 0; c < 8; ++c) {
                o[c] = acc[j][c] + bv[c];
                s_loc[c] += o[c];
                q_loc[c] += o[c] * o[c];
            }
            float4 o0 = {o[0], o[1], o[2], o[3]};
            float4 o1 = {o[4], o[5], o[6], o[7]};
            *(float4*)&h[(size_t)row * 128 + tx8] = o0;
            *(float4*)&h[(size_t)row * 128 + tx8 + 4] = o1;
        }
    }

    // wave-level reduce across the 4 ty-subgroups sharing each tx (lanes ^16, ^32)
#pragma unroll
    for (int c = 0; c < 8; ++c) {
        s_loc[c] += __shfl_xor(s_loc[c], 16, 64);
        s_loc[c] += __shfl_xor(s_loc[c], 32, 64);
        q_loc[c] += __shfl_xor(q_loc[c], 16, 64);
        q_loc[c] += __shfl_xor(q_loc[c], 32, 64);
    }
    int wave = t >> 6;
    if ((t & 63) < 16) {
#pragma unroll
        for (int c = 0; c < 8; ++c) {
            redS[wave][tx8 + c] = s_loc[c];
            redQ[wave][tx8 + c] = q_loc[c];
        }
    }
    __syncthreads();
    if (t < 128) {
        float s = redS[0][t] + redS[1][t] + redS[2][t] + redS[3][t];
        float q = redQ[0][t] + redQ[1][t] + redQ[2][t] + redQ[3][t];
        atomicAdd(&stats[t], s);
        atomicAdd(&stats[128 + t], q);
    }
}

// ============================================================================
// BatchNorm finalize + apply
// ============================================================================
extern "C" __global__
void zero_stats_kernel(float* __restrict__ stats) {
    stats[threadIdx.x] = 0.0f;
}

extern "C" __global__
void finalize_kernel(const float* __restrict__ stats, const float* __restrict__ gamma,
                     const float* __restrict__ beta, float* __restrict__ ss, float inv_n) {
    int c = threadIdx.x;
    if (c < 128) {
        float mu = stats[c] * inv_n;
        float var = stats[128 + c] * inv_n - mu * mu;
        float sc = gamma[c] * rsqrtf(var + EPS_BN);
        ss[c] = sc;
        ss[128 + c] = beta[c] - mu * sc;
    }
}

extern "C" __global__ __launch_bounds__(256)
void bn_relu_kernel(float4* __restrict__ h, const float* __restrict__ ss, long n4) {
    __shared__ float s_ss[256];
    if (threadIdx.x < 256) s_ss[threadIdx.x] = ss[threadIdx.x];
    __syncthreads();
    long i = (long)blockIdx.x * blockDim.x + threadIdx.x;
    long stride = (long)gridDim.x * blockDim.x;
    for (; i < n4; i += stride) {
        int c4 = (int)(i & 31) * 4;
        float4 v = h[i];
        v.x = fmaxf(fmaf(v.x, s_ss[c4 + 0], s_ss[128 + c4 + 0]), 0.f);
        v.y = fmaxf(fmaf(v.y, s_ss[c4 + 1], s_ss[128 + c4 + 1]), 0.f);
        v.z = fmaxf(fmaf(v.z, s_ss[c4 + 2], s_ss[128 + c4 + 2]), 0.f);
        v.w = fmaxf(fmaf(v.w, s_ss[c4 + 3], s_ss[128 + c4 + 3]), 0.f);
        h[i] = v;
    }
}

// ============================================================================
// host-side orchestration
// ============================================================================
static void run_layer_ll(const float* in_feat, const int* head, const int* next,
                         const int* ei, int Nn,
                         const float* Wl, const float* bl, const float* Wr,
                         const float* gamma, const float* beta,
                         float* agg, float* stats, float* ss,
                         float* out, hipStream_t stream) {
    long n4 = (long)Nn * 32;

    zero_stats_kernel<<<1, 256, 0, stream>>>(stats);
    gather_max_ll_kernel<<<(Nn * 32 + 255) / 256, 256, 0, stream>>>(
        (const float4*)in_feat, head, next, ei, (float4*)agg, Nn);
    gemm_kernel<<<(Nn + 63) / 64, 256, 0, stream>>>(agg, in_feat, Wl, Wr, bl,
                                                    out, stats, Nn);
    finalize_kernel<<<1, 128, 0, stream>>>(stats, gamma, beta, ss, 1.0f / (float)Nn);
    int bnBlocks = (int)((n4 + 255) / 256);
    if (bnBlocks > 8192) bnBlocks = 8192;
    bn_relu_kernel<<<bnBlocks, 256, 0, stream>>>((float4*)out, ss, n4);
}

static void run_layer_atomic(const float* in_feat, const int* ei, int Nn, int Ee,
                             const float* Wl, const float* bl, const float* Wr,
                             const float* gamma, const float* beta,
                             float* agg, float* stats, float* ss,
                             float* out, hipStream_t stream) {
    long aggN = (long)Nn * 128;
    long n4 = aggN / 4;

    zero_stats_kernel<<<1, 256, 0, stream>>>(stats);
    int initBlocks = (int)((n4 + 255) / 256);
    if (initBlocks > 4096) initBlocks = 4096;
    init_sentinel_kernel<<<initBlocks, 256, 0, stream>>>((uint4*)agg, n4);
    int sb = (int)(((long)Ee * 32 + 255) / 256);
    scatter_max_kernel<<<sb, 256, 0, stream>>>((const float4*)in_feat, ei,
                                               (unsigned*)agg, Ee);
    int ub = (int)((aggN + 255) / 256);
    if (ub > 8192) ub = 8192;
    unmap_kernel<<<ub, 256, 0, stream>>>((unsigned*)agg, aggN);
    gemm_kernel<<<(Nn + 63) / 64, 256, 0, stream>>>(agg, in_feat, Wl, Wr, bl,
                                                    out, stats, Nn);
    finalize_kernel<<<1, 128, 0, stream>>>(stats, gamma, beta, ss, 1.0f / (float)Nn);
    int bnBlocks = (int)((n4 + 255) / 256);
    if (bnBlocks > 8192) bnBlocks = 8192;
    bn_relu_kernel<<<bnBlocks, 256, 0, stream>>>((float4*)out, ss, n4);
}

extern "C" void kernel_launch(void* const* d_in, const int* in_sizes, int n_in,
                              void* d_out, int out_size, void* d_ws, size_t ws_size,
                              hipStream_t stream) {
    (void)n_in; (void)out_size;
    const float* x     = (const float*)d_in[0];
    const int*   ei    = (const int*)d_in[1];
    const float* W0_l  = (const float*)d_in[2];
    const float* b0_l  = (const float*)d_in[3];
    const float* W0_r  = (const float*)d_in[4];
    const float* g0    = (const float*)d_in[5];
    const float* be0   = (const float*)d_in[6];
    const float* W1_l  = (const float*)d_in[7];
    const float* b1_l  = (const float*)d_in[8];
    const float* W1_r  = (const float*)d_in[9];
    const float* g1    = (const float*)d_in[10];
    const float* be1   = (const float*)d_in[11];

    int Nn = in_sizes[0] / 128;
    int Ee = in_sizes[1] / 2;

    size_t aggBytes = (size_t)Nn * 128 * sizeof(float);
    char* p = (char*)d_ws;
    float* agg = (float*)p;              p += aggBytes;
    float* stats = (float*)p;            p += 256 * sizeof(float);
    float* ss = (float*)p;               p += 256 * sizeof(float);
    int* head = (int*)p;                 p += (size_t)Nn * sizeof(int);
    int* next = (int*)p;                 p += (size_t)Ee * sizeof(int);
    size_t needed = (size_t)(p - (char*)d_ws);
    float* out = (float*)d_out;

    if (ws_size >= needed) {
        // ---- linked-list path ----
        init_head_kernel<<<(Nn + 255) / 256, 256, 0, stream>>>(head, Nn);
        link_kernel<<<(Ee + 255) / 256, 256, 0, stream>>>(ei, head, next, Ee);

        run_layer_ll(x, head, next, ei, Nn, W0_l, b0_l, W0_r, g0, be0,
                     agg, stats, ss, out, stream);
        run_layer_ll(out, head, next, ei, Nn, W1_l, b1_l, W1_r, g1, be1,
                     agg, stats, ss, out, stream);
    } else {
        // ---- fallback: atomic path ----
        run_layer_atomic(x, ei, Nn, Ee, W0_l, b0_l, W0_r, g0, be0,
                         agg, stats, ss, out, stream);
        run_layer_atomic(out, ei, Nn, Ee, W1_l, b1_l, W1_r, g1, be1,
                         agg, stats, ss, out, stream);
    }
}

// Round 5
// 464.046 us; speedup vs baseline: 9.7009x; 1.4120x over previous
//
#include <hip/hip_runtime.h>
#include <stdint.h>

#define EPS_BN 1e-5f

typedef __attribute__((ext_vector_type(8))) short short8v;   // 8 bf16 = 4 VGPR
typedef __attribute__((ext_vector_type(4))) float f32x4;     // MFMA accumulator

__device__ __forceinline__ unsigned rne_bf16(float f) {      // round-to-nearest-even
    unsigned u = __float_as_uint(f);
    return (u + 0x7FFFu + ((u >> 16) & 1u)) >> 16;
}

// ============================================================================
// prep: fp32 -> bf16 feature conversion, weight transpose+concat to bf16
// ============================================================================
extern "C" __global__ __launch_bounds__(256)
void f32_to_bf16_kernel(const float4* __restrict__ in, uint2* __restrict__ out, long n4) {
    long i = (long)blockIdx.x * 256 + threadIdx.x;
    long stride = (long)gridDim.x * 256;
    for (; i < n4; i += stride) {
        float4 v = in[i];
        uint2 o;
        o.x = rne_bf16(v.x) | (rne_bf16(v.y) << 16);
        o.y = rne_bf16(v.z) | (rne_bf16(v.w) << 16);
        out[i] = o;
    }
}

// Wt[col][k] (k in [0,256): k<128 -> Wl[k][col], else Wr[k-128][col]), bf16
extern "C" __global__ __launch_bounds__(256)
void wt_prep_kernel(const float* __restrict__ Wl, const float* __restrict__ Wr,
                    unsigned short* __restrict__ Wt) {
    int idx = blockIdx.x * 256 + threadIdx.x;      // 128*256 = 32768 total
    int col = idx >> 8, k = idx & 255;
    float v = (k < 128) ? Wl[(size_t)k * 128 + col] : Wr[(size_t)(k - 128) * 128 + col];
    Wt[(size_t)col * 256 + k] = (unsigned short)rne_bf16(v);
}

// ============================================================================
// linked-list build (once; shared by both layers)
// ============================================================================
extern "C" __global__ __launch_bounds__(256)
void init_head_kernel(int* __restrict__ head, int n) {
    int i = blockIdx.x * 256 + threadIdx.x;
    if (i < n) head[i] = -1;
}

extern "C" __global__ __launch_bounds__(256)
void link_kernel(const int* __restrict__ ei, int* __restrict__ head,
                 int* __restrict__ next, int E) {
    int e = blockIdx.x * 256 + threadIdx.x;
    if (e < E) {
        int dst = ei[E + e];
        int old = atomicExch(&head[dst], e);
        next[e] = old;
    }
}

// ============================================================================
// gather-max over bf16 rows: 32 lanes/node, uint2 (4 bf16 = 8B) per lane
// max over bf16 values done in f32 space (exact); result repacked bf16.
// ============================================================================
extern "C" __global__ __launch_bounds__(256)
void gather_max_ll16_kernel(const uint2* __restrict__ x16, const int* __restrict__ head,
                            const int* __restrict__ next, const int* __restrict__ ei,
                            uint2* __restrict__ agg16, int Nn) {
    int t = blockIdx.x * 256 + threadIdx.x;
    int node = t >> 5;
    if (node >= Nn) return;
    int lane = t & 31;
    int e = head[node];
    uint2 out;
    if (e >= 0) {
        int src = ei[e];
        int en = next[e];
        uint2 u = x16[(size_t)src * 32 + lane];
        float a0 = __uint_as_float(u.x << 16);
        float a1 = __uint_as_float(u.x & 0xFFFF0000u);
        float a2 = __uint_as_float(u.y << 16);
        float a3 = __uint_as_float(u.y & 0xFFFF0000u);
        while (en >= 0) {
            int s2 = ei[en];
            int en2 = next[en];
            uint2 v = x16[(size_t)s2 * 32 + lane];
            en = en2;
            a0 = fmaxf(a0, __uint_as_float(v.x << 16));
            a1 = fmaxf(a1, __uint_as_float(v.x & 0xFFFF0000u));
            a2 = fmaxf(a2, __uint_as_float(v.y << 16));
            a3 = fmaxf(a3, __uint_as_float(v.y & 0xFFFF0000u));
        }
        out.x = (__float_as_uint(a0) >> 16) | (__float_as_uint(a1) & 0xFFFF0000u);
        out.y = (__float_as_uint(a2) >> 16) | (__float_as_uint(a3) & 0xFFFF0000u);
    } else {
        out.x = 0u; out.y = 0u;    // PyG fills empty segments with 0
    }
    agg16[(size_t)node * 32 + lane] = out;
}

// ============================================================================
// MFMA GEMM: h = [agg16 | xin16] @ Wt^T + bias, fused BN col-stats
// 256 thr = 4 waves (2x2), BM=128, BN=128, per wave 64x64 (4x4 frags 16x16),
// K=256 in 8 steps of 32. A/B fragments loaded straight from global (16B).
// ============================================================================
extern "C" __global__ __launch_bounds__(256)
void gemm_bf16_kernel(const unsigned short* __restrict__ agg16,
                      const unsigned short* __restrict__ xin16,
                      const unsigned short* __restrict__ Wt,
                      const float* __restrict__ bias,
                      float* __restrict__ h, float* __restrict__ stats, int nrows) {
    __shared__ float redS[4][128];
    __shared__ float redQ[4][128];

    const int t = threadIdx.x;
    const int w = t >> 6, l = t & 63;
    const int wm = w >> 1, wn = w & 1;
    const int r16 = l & 15, g = l >> 4;
    const int blockRow = blockIdx.x * 128;
    const int colBase = wn * 64;

    f32x4 acc[4][4];
#pragma unroll
    for (int m = 0; m < 4; ++m)
#pragma unroll
        for (int n = 0; n < 4; ++n) acc[m][n] = (f32x4){0.f, 0.f, 0.f, 0.f};

    const short8v az = {0, 0, 0, 0, 0, 0, 0, 0};

#pragma unroll
    for (int kt = 0; kt < 8; ++kt) {
        const unsigned short* Asrc = (kt < 4) ? agg16 : xin16;
        const int kofs = (kt < 4) ? kt * 32 : kt * 32 - 128;

        short8v b[4];
#pragma unroll
        for (int n = 0; n < 4; ++n) {
            int col = colBase + n * 16 + r16;
            b[n] = *(const short8v*)(Wt + (size_t)col * 256 + kt * 32 + g * 8);
        }
        short8v a[4];
#pragma unroll
        for (int m = 0; m < 4; ++m) {
            int row = blockRow + wm * 64 + m * 16 + r16;
            a[m] = (row < nrows)
                 ? *(const short8v*)(Asrc + (size_t)row * 128 + kofs + g * 8)
                 : az;
        }
#pragma unroll
        for (int m = 0; m < 4; ++m)
#pragma unroll
            for (int n = 0; n < 4; ++n)
                acc[m][n] = __builtin_amdgcn_mfma_f32_16x16x32_bf16(a[m], b[n], acc[m][n], 0, 0, 0);
    }

    // ---- epilogue: bias, store h, fused BN stats ----
    for (int i = t; i < 512; i += 256) {
        ((float*)redS)[i] = 0.f;
        ((float*)redQ)[i] = 0.f;
    }
    __syncthreads();

    float bcol[4];
#pragma unroll
    for (int n = 0; n < 4; ++n) bcol[n] = bias[colBase + n * 16 + r16];

    float s4[4] = {0.f, 0.f, 0.f, 0.f};
    float q4[4] = {0.f, 0.f, 0.f, 0.f};
#pragma unroll
    for (int m = 0; m < 4; ++m) {
#pragma unroll
        for (int reg = 0; reg < 4; ++reg) {
            int row = blockRow + wm * 64 + m * 16 + g * 4 + reg;   // C/D: row=(l>>4)*4+reg
            if (row < nrows) {
#pragma unroll
                for (int n = 0; n < 4; ++n) {
                    float o = acc[m][n][reg] + bcol[n];
                    h[(size_t)row * 128 + colBase + n * 16 + r16] = o;   // col=l&15
                    s4[n] += o;
                    q4[n] += o * o;
                }
            }
        }
    }
#pragma unroll
    for (int n = 0; n < 4; ++n) {     // reduce over the 4 k-groups (same col)
        s4[n] += __shfl_xor(s4[n], 16, 64);
        s4[n] += __shfl_xor(s4[n], 32, 64);
        q4[n] += __shfl_xor(q4[n], 16, 64);
        q4[n] += __shfl_xor(q4[n], 32, 64);
    }
    if (g == 0) {
#pragma unroll
        for (int n = 0; n < 4; ++n) {
            redS[w][colBase + n * 16 + r16] = s4[n];
            redQ[w][colBase + n * 16 + r16] = q4[n];
        }
    }
    __syncthreads();
    if (t < 128) {
        float s = redS[0][t] + redS[1][t] + redS[2][t] + redS[3][t];
        float q = redQ[0][t] + redQ[1][t] + redQ[2][t] + redQ[3][t];
        atomicAdd(&stats[t], s);
        atomicAdd(&stats[128 + t], q);
    }
}

// ============================================================================
// BatchNorm finalize + apply
// ============================================================================
extern "C" __global__
void zero_stats_kernel(float* __restrict__ stats) {
    stats[threadIdx.x] = 0.0f;
}

extern "C" __global__
void finalize_kernel(const float* __restrict__ stats, const float* __restrict__ gamma,
                     const float* __restrict__ beta, float* __restrict__ ss, float inv_n) {
    int c = threadIdx.x;
    if (c < 128) {
        float mu = stats[c] * inv_n;
        float var = stats[128 + c] * inv_n - mu * mu;
        float sc = gamma[c] * rsqrtf(var + EPS_BN);
        ss[c] = sc;
        ss[128 + c] = beta[c] - mu * sc;
    }
}

// BN+ReLU -> bf16 output only (layer-1 intermediate for layer 2)
extern "C" __global__ __launch_bounds__(256)
void bn_relu_tobf16_kernel(const float4* __restrict__ h, const float* __restrict__ ss,
                           uint2* __restrict__ y16, long n4) {
    __shared__ float s_ss[256];
    if (threadIdx.x < 256) s_ss[threadIdx.x] = ss[threadIdx.x];
    __syncthreads();
    long i = (long)blockIdx.x * blockDim.x + threadIdx.x;
    long stride = (long)gridDim.x * blockDim.x;
    for (; i < n4; i += stride) {
        int c4 = (int)(i & 31) * 4;
        float4 v = h[i];
        float o0 = fmaxf(fmaf(v.x, s_ss[c4 + 0], s_ss[128 + c4 + 0]), 0.f);
        float o1 = fmaxf(fmaf(v.y, s_ss[c4 + 1], s_ss[128 + c4 + 1]), 0.f);
        float o2 = fmaxf(fmaf(v.z, s_ss[c4 + 2], s_ss[128 + c4 + 2]), 0.f);
        float o3 = fmaxf(fmaf(v.w, s_ss[c4 + 3], s_ss[128 + c4 + 3]), 0.f);
        uint2 o;
        o.x = rne_bf16(o0) | (rne_bf16(o1) << 16);
        o.y = rne_bf16(o2) | (rne_bf16(o3) << 16);
        y16[i] = o;
    }
}

// BN+ReLU in place fp32 (final output)
extern "C" __global__ __launch_bounds__(256)
void bn_relu_kernel(float4* __restrict__ h, const float* __restrict__ ss, long n4) {
    __shared__ float s_ss[256];
    if (threadIdx.x < 256) s_ss[threadIdx.x] = ss[threadIdx.x];
    __syncthreads();
    long i = (long)blockIdx.x * blockDim.x + threadIdx.x;
    long stride = (long)gridDim.x * blockDim.x;
    for (; i < n4; i += stride) {
        int c4 = (int)(i & 31) * 4;
        float4 v = h[i];
        v.x = fmaxf(fmaf(v.x, s_ss[c4 + 0], s_ss[128 + c4 + 0]), 0.f);
        v.y = fmaxf(fmaf(v.y, s_ss[c4 + 1], s_ss[128 + c4 + 1]), 0.f);
        v.z = fmaxf(fmaf(v.z, s_ss[c4 + 2], s_ss[128 + c4 + 2]), 0.f);
        v.w = fmaxf(fmaf(v.w, s_ss[c4 + 3], s_ss[128 + c4 + 3]), 0.f);
        h[i] = v;
    }
}

// ============================================================================
// fallback path (fp32 atomic scatter-max + VALU GEMM) — only if ws too small
// ============================================================================
__device__ __forceinline__ unsigned map_f(float f) {
    unsigned u = __float_as_uint(f);
    return (u & 0x80000000u) ? ~u : (u | 0x80000000u);
}
__device__ __forceinline__ float unmap_f(unsigned m) {
    return (m & 0x80000000u) ? __uint_as_float(m & 0x7FFFFFFFu) : __uint_as_float(~m);
}

extern "C" __global__ __launch_bounds__(256)
void init_sentinel_kernel(uint4* __restrict__ agg, long n4) {
    uint4 z = {0u, 0u, 0u, 0u};
    long i = (long)blockIdx.x * blockDim.x + threadIdx.x;
    long stride = (long)gridDim.x * blockDim.x;
    for (; i < n4; i += stride) agg[i] = z;
}

extern "C" __global__ __launch_bounds__(256)
void scatter_max_kernel(const float4* __restrict__ xin, const int* __restrict__ ei,
                        unsigned* __restrict__ agg, int E) {
    int t = blockIdx.x * 256 + threadIdx.x;
    int e = t >> 5;
    if (e >= E) return;
    int f4 = t & 31;
    int src = ei[e];
    int dst = ei[E + e];
    float4 v = xin[(size_t)src * 32 + f4];
    unsigned* p = agg + (size_t)dst * 128 + (size_t)f4 * 4;
    atomicMax(p + 0, map_f(v.x));
    atomicMax(p + 1, map_f(v.y));
    atomicMax(p + 2, map_f(v.z));
    atomicMax(p + 3, map_f(v.w));
}

extern "C" __global__ __launch_bounds__(256)
void unmap_kernel(unsigned* __restrict__ agg, long n) {
    long i = (long)blockIdx.x * blockDim.x + threadIdx.x;
    long stride = (long)gridDim.x * blockDim.x;
    for (; i < n; i += stride) {
        unsigned u = agg[i];
        agg[i] = __float_as_uint(u ? unmap_f(u) : 0.0f);
    }
}

extern "C" __global__ __launch_bounds__(256)
void gemm_kernel(const float* __restrict__ agg, const float* __restrict__ xin,
                 const float* __restrict__ Wl, const float* __restrict__ Wr,
                 const float* __restrict__ bias, float* __restrict__ h,
                 float* __restrict__ stats, int nrows) {
    __shared__ __align__(16) float As[64][36];
    __shared__ __align__(16) float Bs[32][136];
    __shared__ float redS[4][128];
    __shared__ float redQ[4][128];

    const int t = threadIdx.x;
    const int tx = t & 15;
    const int ty = t >> 4;
    const int tx8 = tx * 8;
    const int ty4 = ty * 4;
    const int blockRow = blockIdx.x * 64;

    float acc[4][8];
#pragma unroll
    for (int j = 0; j < 4; ++j)
#pragma unroll
        for (int c = 0; c < 8; ++c) acc[j][c] = 0.0f;

    for (int kt = 0; kt < 8; ++kt) {
        const int k0 = kt * 32;
        const bool isAgg = (kt < 4);
        const float* W = isAgg ? Wl : Wr;
        const float* Asrc = isAgg ? agg : xin;
        const int kw = isAgg ? k0 : (k0 - 128);

#pragma unroll
        for (int it = 0; it < 4; ++it) {
            int idx = t + it * 256;
            int kr = idx >> 5, cq = idx & 31;
            float4 ww = *(const float4*)&W[(size_t)(kw + kr) * 128 + cq * 4];
            *(float4*)&Bs[kr][cq * 4] = ww;
        }
#pragma unroll
        for (int it = 0; it < 2; ++it) {
            int idx = t + it * 256;
            int r = idx >> 3, kq = idx & 7;
            int row_g = blockRow + r;
            float4 a = {0.f, 0.f, 0.f, 0.f};
            if (row_g < nrows)
                a = *(const float4*)&Asrc[(size_t)row_g * 128 + kw + kq * 4];
            *(float4*)&As[r][kq * 4] = a;
        }
        __syncthreads();

#pragma unroll
        for (int kk = 0; kk < 32; ++kk) {
            float aa[4];
            aa[0] = As[ty4 + 0][kk];
            aa[1] = As[ty4 + 1][kk];
            aa[2] = As[ty4 + 2][kk];
            aa[3] = As[ty4 + 3][kk];
            float4 b0 = *(const float4*)&Bs[kk][tx8];
            float4 b1 = *(const float4*)&Bs[kk][tx8 + 4];
            float bb[8] = {b0.x, b0.y, b0.z, b0.w, b1.x, b1.y, b1.z, b1.w};
#pragma unroll
            for (int j = 0; j < 4; ++j)
#pragma unroll
                for (int c = 0; c < 8; ++c)
                    acc[j][c] = fmaf(aa[j], bb[c], acc[j][c]);
        }
        __syncthreads();
    }

    float bv[8];
#pragma unroll
    for (int c = 0; c < 8; ++c) bv[c] = bias[tx8 + c];

    float s_loc[8], q_loc[8];
#pragma unroll
    for (int c = 0; c < 8; ++c) { s_loc[c] = 0.f; q_loc[c] = 0.f; }

#pragma unroll
    for (int j = 0; j < 4; ++j) {
        int row = blockRow + ty4 + j;
        if (row < nrows) {
            float o[8];
#pragma unroll
            for (int c = 0; c < 8; ++c) {
                o[c] = acc[j][c] + bv[c];
                s_loc[c] += o[c];
                q_loc[c] += o[c] * o[c];
            }
            float4 o0 = {o[0], o[1], o[2], o[3]};
            float4 o1 = {o[4], o[5], o[6], o[7]};
            *(float4*)&h[(size_t)row * 128 + tx8] = o0;
            *(float4*)&h[(size_t)row * 128 + tx8 + 4] = o1;
        }
    }

#pragma unroll
    for (int c = 0; c < 8; ++c) {
        s_loc[c] += __shfl_xor(s_loc[c], 16, 64);
        s_loc[c] += __shfl_xor(s_loc[c], 32, 64);
        q_loc[c] += __shfl_xor(q_loc[c], 16, 64);
        q_loc[c] += __shfl_xor(q_loc[c], 32, 64);
    }
    int wave = t >> 6;
    if ((t & 63) < 16) {
#pragma unroll
        for (int c = 0; c < 8; ++c) {
            redS[wave][tx8 + c] = s_loc[c];
            redQ[wave][tx8 + c] = q_loc[c];
        }
    }
    __syncthreads();
    if (t < 128) {
        float s = redS[0][t] + redS[1][t] + redS[2][t] + redS[3][t];
        float q = redQ[0][t] + redQ[1][t] + redQ[2][t] + redQ[3][t];
        atomicAdd(&stats[t], s);
        atomicAdd(&stats[128 + t], q);
    }
}

// ============================================================================
// host-side orchestration
// ============================================================================
static void run_layer_bf16(const unsigned short* in16, const int* head, const int* next,
                           const int* ei, int Nn,
                           const unsigned short* Wt, const float* bl,
                           const float* gamma, const float* beta,
                           unsigned short* agg16, float* stats, float* ss,
                           float* h, hipStream_t stream) {
    zero_stats_kernel<<<1, 256, 0, stream>>>(stats);
    gather_max_ll16_kernel<<<(Nn * 32 + 255) / 256, 256, 0, stream>>>(
        (const uint2*)in16, head, next, ei, (uint2*)agg16, Nn);
    gemm_bf16_kernel<<<(Nn + 127) / 128, 256, 0, stream>>>(agg16, in16, Wt, bl,
                                                           h, stats, Nn);
    finalize_kernel<<<1, 128, 0, stream>>>(stats, gamma, beta, ss, 1.0f / (float)Nn);
}

static void run_layer_atomic(const float* in_feat, const int* ei, int Nn, int Ee,
                             const float* Wl, const float* bl, const float* Wr,
                             const float* gamma, const float* beta,
                             float* agg, float* stats, float* ss,
                             float* out, hipStream_t stream) {
    long aggN = (long)Nn * 128;
    long n4 = aggN / 4;

    zero_stats_kernel<<<1, 256, 0, stream>>>(stats);
    int initBlocks = (int)((n4 + 255) / 256);
    if (initBlocks > 4096) initBlocks = 4096;
    init_sentinel_kernel<<<initBlocks, 256, 0, stream>>>((uint4*)agg, n4);
    int sb = (int)(((long)Ee * 32 + 255) / 256);
    scatter_max_kernel<<<sb, 256, 0, stream>>>((const float4*)in_feat, ei,
                                               (unsigned*)agg, Ee);
    int ub = (int)((aggN + 255) / 256);
    if (ub > 8192) ub = 8192;
    unmap_kernel<<<ub, 256, 0, stream>>>((unsigned*)agg, aggN);
    gemm_kernel<<<(Nn + 63) / 64, 256, 0, stream>>>(agg, in_feat, Wl, Wr, bl,
                                                    out, stats, Nn);
    finalize_kernel<<<1, 128, 0, stream>>>(stats, gamma, beta, ss, 1.0f / (float)Nn);
    int bnBlocks = (int)((n4 + 255) / 256);
    if (bnBlocks > 8192) bnBlocks = 8192;
    bn_relu_kernel<<<bnBlocks, 256, 0, stream>>>((float4*)out, ss, n4);
}

extern "C" void kernel_launch(void* const* d_in, const int* in_sizes, int n_in,
                              void* d_out, int out_size, void* d_ws, size_t ws_size,
                              hipStream_t stream) {
    (void)n_in; (void)out_size;
    const float* x     = (const float*)d_in[0];
    const int*   ei    = (const int*)d_in[1];
    const float* W0_l  = (const float*)d_in[2];
    const float* b0_l  = (const float*)d_in[3];
    const float* W0_r  = (const float*)d_in[4];
    const float* g0    = (const float*)d_in[5];
    const float* be0   = (const float*)d_in[6];
    const float* W1_l  = (const float*)d_in[7];
    const float* b1_l  = (const float*)d_in[8];
    const float* W1_r  = (const float*)d_in[9];
    const float* g1    = (const float*)d_in[10];
    const float* be1   = (const float*)d_in[11];

    int Nn = in_sizes[0] / 128;
    int Ee = in_sizes[1] / 2;
    long n4 = (long)Nn * 32;                   // float4 / uint2 row-elems

    char* p = (char*)d_ws;
    unsigned short* xy16 = (unsigned short*)p;  p += (size_t)Nn * 128 * 2;  // x16, later y16
    unsigned short* agg16 = (unsigned short*)p; p += (size_t)Nn * 128 * 2;
    float* stats = (float*)p;                   p += 256 * sizeof(float);
    float* ss = (float*)p;                      p += 256 * sizeof(float);
    unsigned short* Wt0 = (unsigned short*)p;   p += 128 * 256 * 2;
    unsigned short* Wt1 = (unsigned short*)p;   p += 128 * 256 * 2;
    int* head = (int*)p;                        p += (size_t)Nn * sizeof(int);
    int* next = (int*)p;                        p += (size_t)Ee * sizeof(int);
    size_t needed = (size_t)(p - (char*)d_ws);
    float* out = (float*)d_out;

    if (ws_size >= needed) {
        // ---- bf16 MFMA path ----
        int cvB = (int)((n4 + 255) / 256);
        if (cvB > 4096) cvB = 4096;
        f32_to_bf16_kernel<<<cvB, 256, 0, stream>>>((const float4*)x, (uint2*)xy16, n4);
        wt_prep_kernel<<<128, 256, 0, stream>>>(W0_l, W0_r, Wt0);
        wt_prep_kernel<<<128, 256, 0, stream>>>(W1_l, W1_r, Wt1);
        init_head_kernel<<<(Nn + 255) / 256, 256, 0, stream>>>(head, Nn);
        link_kernel<<<(Ee + 255) / 256, 256, 0, stream>>>(ei, head, next, Ee);

        // layer 1: h1 -> d_out (scratch), y1(bf16) -> xy16 (x16 is dead after gemm)
        run_layer_bf16(xy16, head, next, ei, Nn, Wt0, b0_l, g0, be0,
                       agg16, stats, ss, out, stream);
        int bnB = (int)((n4 + 255) / 256);
        if (bnB > 8192) bnB = 8192;
        bn_relu_tobf16_kernel<<<bnB, 256, 0, stream>>>((const float4*)out, ss,
                                                       (uint2*)xy16, n4);
        // layer 2: h2 -> d_out, final BN+ReLU in place (fp32)
        run_layer_bf16(xy16, head, next, ei, Nn, Wt1, b1_l, g1, be1,
                       agg16, stats, ss, out, stream);
        bn_relu_kernel<<<bnB, 256, 0, stream>>>((float4*)out, ss, n4);
    } else {
        // ---- fallback: fp32 atomic path ----
        float* agg = (float*)d_ws;
        float* fstats = (float*)((char*)d_ws + (size_t)Nn * 128 * sizeof(float));
        float* fss = fstats + 256;
        run_layer_atomic(x, ei, Nn, Ee, W0_l, b0_l, W0_r, g0, be0,
                         agg, fstats, fss, out, stream);
        run_layer_atomic(out, ei, Nn, Ee, W1_l, b1_l, W1_r, g1, be1,
                         agg, fstats, fss, out, stream);
    }
}

// Round 6
// 405.836 us; speedup vs baseline: 11.0923x; 1.1434x over previous
//
#include <hip/hip_runtime.h>
#include <stdint.h>

#define EPS_BN 1e-5f

typedef __attribute__((ext_vector_type(8))) short short8v;   // 8 bf16 = 4 VGPR
typedef __attribute__((ext_vector_type(4))) float f32x4;     // MFMA accumulator

__device__ __forceinline__ unsigned rne_bf16(float f) {      // round-to-nearest-even
    unsigned u = __float_as_uint(f);
    return (u + 0x7FFFu + ((u >> 16) & 1u)) >> 16;
}

// ============================================================================
// prep: fp32 -> bf16 feature conversion, weight transpose+concat to bf16
// ============================================================================
extern "C" __global__ __launch_bounds__(256)
void f32_to_bf16_kernel(const float4* __restrict__ in, uint2* __restrict__ out, long n4) {
    long i = (long)blockIdx.x * 256 + threadIdx.x;
    long stride = (long)gridDim.x * 256;
    for (; i < n4; i += stride) {
        float4 v = in[i];
        uint2 o;
        o.x = rne_bf16(v.x) | (rne_bf16(v.y) << 16);
        o.y = rne_bf16(v.z) | (rne_bf16(v.w) << 16);
        out[i] = o;
    }
}

// Wt[col][k] (k in [0,256): k<128 -> Wl[k][col], else Wr[k-128][col]), bf16
extern "C" __global__ __launch_bounds__(256)
void wt_prep_kernel(const float* __restrict__ Wl, const float* __restrict__ Wr,
                    unsigned short* __restrict__ Wt) {
    int idx = blockIdx.x * 256 + threadIdx.x;      // 128*256 = 32768 total
    int col = idx >> 8, k = idx & 255;
    float v = (k < 128) ? Wl[(size_t)k * 128 + col] : Wr[(size_t)(k - 128) * 128 + col];
    Wt[(size_t)col * 256 + k] = (unsigned short)rne_bf16(v);
}

// ============================================================================
// linked-list build (once; shared by both layers)
//   head[dst] -> most recent edge, pair[e] = (src, prev edge with same dst)
// ============================================================================
extern "C" __global__ __launch_bounds__(256)
void init_head_kernel(int* __restrict__ head, int n) {
    int i = blockIdx.x * 256 + threadIdx.x;
    if (i < n) head[i] = -1;
}

extern "C" __global__ __launch_bounds__(256)
void link_kernel(const int* __restrict__ ei, int* __restrict__ head,
                 uint2* __restrict__ pair, int E) {
    int e = blockIdx.x * 256 + threadIdx.x;
    if (e < E) {
        int src = ei[e];
        int dst = ei[E + e];
        int old = atomicExch(&head[dst], e);
        uint2 p; p.x = (unsigned)src; p.y = (unsigned)old;
        pair[e] = p;                 // coalesced 8B write
    }
}

// ============================================================================
// gather-max over bf16 rows: 16 lanes/node, uint4 (8 bf16 = 16B) per lane.
// fmax trick: hi bf16 of each u32 compared as raw u32-as-float (low-16 garbage
// is sub-ulp and can't flip an ordering between distinct bf16 values; ties
// truncate to the same bf16). lo bf16 via exact (u<<16).
// Also zeroes stats[0..255] from block 0 (fused, saves a launch).
// ============================================================================
extern "C" __global__ __launch_bounds__(256, 8)
void gather_max_ll16_kernel(const uint4* __restrict__ x16r, const int* __restrict__ head,
                            const uint2* __restrict__ pair,
                            uint4* __restrict__ agg16, float* __restrict__ stats, int Nn) {
    if (blockIdx.x == 0 && threadIdx.x < 256) stats[threadIdx.x] = 0.0f;
    int t = blockIdx.x * 256 + threadIdx.x;
    int node = t >> 4;
    if (node >= Nn) return;
    int lane = t & 15;
    int e = head[node];
    uint4 out;
    if (e >= 0) {
        uint2 p = pair[e];
        uint4 r = x16r[(size_t)p.x * 16 + lane];
        float a0 = __uint_as_float(r.x << 16), a1 = __uint_as_float(r.x);
        float a2 = __uint_as_float(r.y << 16), a3 = __uint_as_float(r.y);
        float a4 = __uint_as_float(r.z << 16), a5 = __uint_as_float(r.z);
        float a6 = __uint_as_float(r.w << 16), a7 = __uint_as_float(r.w);
        int en = (int)p.y;
        while (en >= 0) {
            uint2 pn = pair[en];                       // single dependent 8B load
            uint4 v = x16r[(size_t)pn.x * 16 + lane];  // row load, overlaps chase
            en = (int)pn.y;
            a0 = fmaxf(a0, __uint_as_float(v.x << 16));
            a1 = fmaxf(a1, __uint_as_float(v.x));
            a2 = fmaxf(a2, __uint_as_float(v.y << 16));
            a3 = fmaxf(a3, __uint_as_float(v.y));
            a4 = fmaxf(a4, __uint_as_float(v.z << 16));
            a5 = fmaxf(a5, __uint_as_float(v.z));
            a6 = fmaxf(a6, __uint_as_float(v.w << 16));
            a7 = fmaxf(a7, __uint_as_float(v.w));
        }
        out.x = (__float_as_uint(a0) >> 16) | (__float_as_uint(a1) & 0xFFFF0000u);
        out.y = (__float_as_uint(a2) >> 16) | (__float_as_uint(a3) & 0xFFFF0000u);
        out.z = (__float_as_uint(a4) >> 16) | (__float_as_uint(a5) & 0xFFFF0000u);
        out.w = (__float_as_uint(a6) >> 16) | (__float_as_uint(a7) & 0xFFFF0000u);
    } else {
        out.x = out.y = out.z = out.w = 0u;   // PyG fills empty segments with 0
    }
    agg16[(size_t)node * 16 + lane] = out;
}

// ============================================================================
// MFMA GEMM: h = [agg16 | xin16] @ Wt^T + bias, fused BN col-stats
// 256 thr = 4 waves (2x2), BM=128, BN=128, per wave 64x64 (4x4 frags 16x16),
// K=256 in 8 steps of 32. A/B fragments loaded straight from global (16B).
// ============================================================================
extern "C" __global__ __launch_bounds__(256)
void gemm_bf16_kernel(const unsigned short* __restrict__ agg16,
                      const unsigned short* __restrict__ xin16,
                      const unsigned short* __restrict__ Wt,
                      const float* __restrict__ bias,
                      float* __restrict__ h, float* __restrict__ stats, int nrows) {
    __shared__ float redS[4][128];
    __shared__ float redQ[4][128];

    const int t = threadIdx.x;
    const int w = t >> 6, l = t & 63;
    const int wm = w >> 1, wn = w & 1;
    const int r16 = l & 15, g = l >> 4;
    const int blockRow = blockIdx.x * 128;
    const int colBase = wn * 64;

    f32x4 acc[4][4];
#pragma unroll
    for (int m = 0; m < 4; ++m)
#pragma unroll
        for (int n = 0; n < 4; ++n) acc[m][n] = (f32x4){0.f, 0.f, 0.f, 0.f};

    const short8v az = {0, 0, 0, 0, 0, 0, 0, 0};

#pragma unroll
    for (int kt = 0; kt < 8; ++kt) {
        const unsigned short* Asrc = (kt < 4) ? agg16 : xin16;
        const int kofs = (kt < 4) ? kt * 32 : kt * 32 - 128;

        short8v b[4];
#pragma unroll
        for (int n = 0; n < 4; ++n) {
            int col = colBase + n * 16 + r16;
            b[n] = *(const short8v*)(Wt + (size_t)col * 256 + kt * 32 + g * 8);
        }
        short8v a[4];
#pragma unroll
        for (int m = 0; m < 4; ++m) {
            int row = blockRow + wm * 64 + m * 16 + r16;
            a[m] = (row < nrows)
                 ? *(const short8v*)(Asrc + (size_t)row * 128 + kofs + g * 8)
                 : az;
        }
#pragma unroll
        for (int m = 0; m < 4; ++m)
#pragma unroll
            for (int n = 0; n < 4; ++n)
                acc[m][n] = __builtin_amdgcn_mfma_f32_16x16x32_bf16(a[m], b[n], acc[m][n], 0, 0, 0);
    }

    // ---- epilogue: bias, store h, fused BN stats ----
    for (int i = t; i < 512; i += 256) {
        ((float*)redS)[i] = 0.f;
        ((float*)redQ)[i] = 0.f;
    }
    __syncthreads();

    float bcol[4];
#pragma unroll
    for (int n = 0; n < 4; ++n) bcol[n] = bias[colBase + n * 16 + r16];

    float s4[4] = {0.f, 0.f, 0.f, 0.f};
    float q4[4] = {0.f, 0.f, 0.f, 0.f};
#pragma unroll
    for (int m = 0; m < 4; ++m) {
#pragma unroll
        for (int reg = 0; reg < 4; ++reg) {
            int row = blockRow + wm * 64 + m * 16 + g * 4 + reg;   // C/D: row=(l>>4)*4+reg
            if (row < nrows) {
#pragma unroll
                for (int n = 0; n < 4; ++n) {
                    float o = acc[m][n][reg] + bcol[n];
                    h[(size_t)row * 128 + colBase + n * 16 + r16] = o;   // col=l&15
                    s4[n] += o;
                    q4[n] += o * o;
                }
            }
        }
    }
#pragma unroll
    for (int n = 0; n < 4; ++n) {     // reduce over the 4 k-groups (same col)
        s4[n] += __shfl_xor(s4[n], 16, 64);
        s4[n] += __shfl_xor(s4[n], 32, 64);
        q4[n] += __shfl_xor(q4[n], 16, 64);
        q4[n] += __shfl_xor(q4[n], 32, 64);
    }
    if (g == 0) {
#pragma unroll
        for (int n = 0; n < 4; ++n) {
            redS[w][colBase + n * 16 + r16] = s4[n];
            redQ[w][colBase + n * 16 + r16] = q4[n];
        }
    }
    __syncthreads();
    if (t < 128) {
        float s = redS[0][t] + redS[1][t] + redS[2][t] + redS[3][t];
        float q = redQ[0][t] + redQ[1][t] + redQ[2][t] + redQ[3][t];
        atomicAdd(&stats[t], s);
        atomicAdd(&stats[128 + t], q);
    }
}

// ============================================================================
// BatchNorm finalize + apply
// ============================================================================
extern "C" __global__
void zero_stats_kernel(float* __restrict__ stats) {
    stats[threadIdx.x] = 0.0f;
}

extern "C" __global__
void finalize_kernel(const float* __restrict__ stats, const float* __restrict__ gamma,
                     const float* __restrict__ beta, float* __restrict__ ss, float inv_n) {
    int c = threadIdx.x;
    if (c < 128) {
        float mu = stats[c] * inv_n;
        float var = stats[128 + c] * inv_n - mu * mu;
        float sc = gamma[c] * rsqrtf(var + EPS_BN);
        ss[c] = sc;
        ss[128 + c] = beta[c] - mu * sc;
    }
}

// BN+ReLU -> bf16 output only (layer-1 intermediate for layer 2)
extern "C" __global__ __launch_bounds__(256)
void bn_relu_tobf16_kernel(const float4* __restrict__ h, const float* __restrict__ ss,
                           uint2* __restrict__ y16, long n4) {
    __shared__ float s_ss[256];
    if (threadIdx.x < 256) s_ss[threadIdx.x] = ss[threadIdx.x];
    __syncthreads();
    long i = (long)blockIdx.x * blockDim.x + threadIdx.x;
    long stride = (long)gridDim.x * blockDim.x;
    for (; i < n4; i += stride) {
        int c4 = (int)(i & 31) * 4;
        float4 v = h[i];
        float o0 = fmaxf(fmaf(v.x, s_ss[c4 + 0], s_ss[128 + c4 + 0]), 0.f);
        float o1 = fmaxf(fmaf(v.y, s_ss[c4 + 1], s_ss[128 + c4 + 1]), 0.f);
        float o2 = fmaxf(fmaf(v.z, s_ss[c4 + 2], s_ss[128 + c4 + 2]), 0.f);
        float o3 = fmaxf(fmaf(v.w, s_ss[c4 + 3], s_ss[128 + c4 + 3]), 0.f);
        uint2 o;
        o.x = rne_bf16(o0) | (rne_bf16(o1) << 16);
        o.y = rne_bf16(o2) | (rne_bf16(o3) << 16);
        y16[i] = o;
    }
}

// BN+ReLU in place fp32 (final output)
extern "C" __global__ __launch_bounds__(256)
void bn_relu_kernel(float4* __restrict__ h, const float* __restrict__ ss, long n4) {
    __shared__ float s_ss[256];
    if (threadIdx.x < 256) s_ss[threadIdx.x] = ss[threadIdx.x];
    __syncthreads();
    long i = (long)blockIdx.x * blockDim.x + threadIdx.x;
    long stride = (long)gridDim.x * blockDim.x;
    for (; i < n4; i += stride) {
        int c4 = (int)(i & 31) * 4;
        float4 v = h[i];
        v.x = fmaxf(fmaf(v.x, s_ss[c4 + 0], s_ss[128 + c4 + 0]), 0.f);
        v.y = fmaxf(fmaf(v.y, s_ss[c4 + 1], s_ss[128 + c4 + 1]), 0.f);
        v.z = fmaxf(fmaf(v.z, s_ss[c4 + 2], s_ss[128 + c4 + 2]), 0.f);
        v.w = fmaxf(fmaf(v.w, s_ss[c4 + 3], s_ss[128 + c4 + 3]), 0.f);
        h[i] = v;
    }
}

// ============================================================================
// fallback path (fp32 atomic scatter-max + VALU GEMM) — only if ws too small
// ============================================================================
__device__ __forceinline__ unsigned map_f(float f) {
    unsigned u = __float_as_uint(f);
    return (u & 0x80000000u) ? ~u : (u | 0x80000000u);
}
__device__ __forceinline__ float unmap_f(unsigned m) {
    return (m & 0x80000000u) ? __uint_as_float(m & 0x7FFFFFFFu) : __uint_as_float(~m);
}

extern "C" __global__ __launch_bounds__(256)
void init_sentinel_kernel(uint4* __restrict__ agg, long n4) {
    uint4 z = {0u, 0u, 0u, 0u};
    long i = (long)blockIdx.x * blockDim.x + threadIdx.x;
    long stride = (long)gridDim.x * blockDim.x;
    for (; i < n4; i += stride) agg[i] = z;
}

extern "C" __global__ __launch_bounds__(256)
void scatter_max_kernel(const float4* __restrict__ xin, const int* __restrict__ ei,
                        unsigned* __restrict__ agg, int E) {
    int t = blockIdx.x * 256 + threadIdx.x;
    int e = t >> 5;
    if (e >= E) return;
    int f4 = t & 31;
    int src = ei[e];
    int dst = ei[E + e];
    float4 v = xin[(size_t)src * 32 + f4];
    unsigned* p = agg + (size_t)dst * 128 + (size_t)f4 * 4;
    atomicMax(p + 0, map_f(v.x));
    atomicMax(p + 1, map_f(v.y));
    atomicMax(p + 2, map_f(v.z));
    atomicMax(p + 3, map_f(v.w));
}

extern "C" __global__ __launch_bounds__(256)
void unmap_kernel(unsigned* __restrict__ agg, long n) {
    long i = (long)blockIdx.x * blockDim.x + threadIdx.x;
    long stride = (long)gridDim.x * blockDim.x;
    for (; i < n; i += stride) {
        unsigned u = agg[i];
        agg[i] = __float_as_uint(u ? unmap_f(u) : 0.0f);
    }
}

extern "C" __global__ __launch_bounds__(256)
void gemm_kernel(const float* __restrict__ agg, const float* __restrict__ xin,
                 const float* __restrict__ Wl, const float* __restrict__ Wr,
                 const float* __restrict__ bias, float* __restrict__ h,
                 float* __restrict__ stats, int nrows) {
    __shared__ __align__(16) float As[64][36];
    __shared__ __align__(16) float Bs[32][136];
    __shared__ float redS[4][128];
    __shared__ float redQ[4][128];

    const int t = threadIdx.x;
    const int tx = t & 15;
    const int ty = t >> 4;
    const int tx8 = tx * 8;
    const int ty4 = ty * 4;
    const int blockRow = blockIdx.x * 64;

    float acc[4][8];
#pragma unroll
    for (int j = 0; j < 4; ++j)
#pragma unroll
        for (int c = 0; c < 8; ++c) acc[j][c] = 0.0f;

    for (int kt = 0; kt < 8; ++kt) {
        const int k0 = kt * 32;
        const bool isAgg = (kt < 4);
        const float* W = isAgg ? Wl : Wr;
        const float* Asrc = isAgg ? agg : xin;
        const int kw = isAgg ? k0 : (k0 - 128);

#pragma unroll
        for (int it = 0; it < 4; ++it) {
            int idx = t + it * 256;
            int kr = idx >> 5, cq = idx & 31;
            float4 ww = *(const float4*)&W[(size_t)(kw + kr) * 128 + cq * 4];
            *(float4*)&Bs[kr][cq * 4] = ww;
        }
#pragma unroll
        for (int it = 0; it < 2; ++it) {
            int idx = t + it * 256;
            int r = idx >> 3, kq = idx & 7;
            int row_g = blockRow + r;
            float4 a = {0.f, 0.f, 0.f, 0.f};
            if (row_g < nrows)
                a = *(const float4*)&Asrc[(size_t)row_g * 128 + kw + kq * 4];
            *(float4*)&As[r][kq * 4] = a;
        }
        __syncthreads();

#pragma unroll
        for (int kk = 0; kk < 32; ++kk) {
            float aa[4];
            aa[0] = As[ty4 + 0][kk];
            aa[1] = As[ty4 + 1][kk];
            aa[2] = As[ty4 + 2][kk];
            aa[3] = As[ty4 + 3][kk];
            float4 b0 = *(const float4*)&Bs[kk][tx8];
            float4 b1 = *(const float4*)&Bs[kk][tx8 + 4];
            float bb[8] = {b0.x, b0.y, b0.z, b0.w, b1.x, b1.y, b1.z, b1.w};
#pragma unroll
            for (int j = 0; j < 4; ++j)
#pragma unroll
                for (int c = 0; c < 8; ++c)
                    acc[j][c] = fmaf(aa[j], bb[c], acc[j][c]);
        }
        __syncthreads();
    }

    float bv[8];
#pragma unroll
    for (int c = 0; c < 8; ++c) bv[c] = bias[tx8 + c];

    float s_loc[8], q_loc[8];
#pragma unroll
    for (int c = 0; c < 8; ++c) { s_loc[c] = 0.f; q_loc[c] = 0.f; }

#pragma unroll
    for (int j = 0; j < 4; ++j) {
        int row = blockRow + ty4 + j;
        if (row < nrows) {
            float o[8];
#pragma unroll
            for (int c = 0; c < 8; ++c) {
                o[c] = acc[j][c] + bv[c];
                s_loc[c] += o[c];
                q_loc[c] += o[c] * o[c];
            }
            float4 o0 = {o[0], o[1], o[2], o[3]};
            float4 o1 = {o[4], o[5], o[6], o[7]};
            *(float4*)&h[(size_t)row * 128 + tx8] = o0;
            *(float4*)&h[(size_t)row * 128 + tx8 + 4] = o1;
        }
    }

#pragma unroll
    for (int c = 0; c < 8; ++c) {
        s_loc[c] += __shfl_xor(s_loc[c], 16, 64);
        s_loc[c] += __shfl_xor(s_loc[c], 32, 64);
        q_loc[c] += __shfl_xor(q_loc[c], 16, 64);
        q_loc[c] += __shfl_xor(q_loc[c], 32, 64);
    }
    int wave = t >> 6;
    if ((t & 63) < 16) {
#pragma unroll
        for (int c = 0; c < 8; ++c) {
            redS[wave][tx8 + c] = s_loc[c];
            redQ[wave][tx8 + c] = q_loc[c];
        }
    }
    __syncthreads();
    if (t < 128) {
        float s = redS[0][t] + redS[1][t] + redS[2][t] + redS[3][t];
        float q = redQ[0][t] + redQ[1][t] + redQ[2][t] + redQ[3][t];
        atomicAdd(&stats[t], s);
        atomicAdd(&stats[128 + t], q);
    }
}

// ============================================================================
// host-side orchestration
// ============================================================================
static void run_layer_bf16(const unsigned short* in16, const int* head, const uint2* pair,
                           int Nn, const unsigned short* Wt, const float* bl,
                           const float* gamma, const float* beta,
                           unsigned short* agg16, float* stats, float* ss,
                           float* h, hipStream_t stream) {
    gather_max_ll16_kernel<<<(Nn * 16 + 255) / 256, 256, 0, stream>>>(
        (const uint4*)in16, head, pair, (uint4*)agg16, stats, Nn);
    gemm_bf16_kernel<<<(Nn + 127) / 128, 256, 0, stream>>>(agg16, in16, Wt, bl,
                                                           h, stats, Nn);
    finalize_kernel<<<1, 128, 0, stream>>>(stats, gamma, beta, ss, 1.0f / (float)Nn);
}

static void run_layer_atomic(const float* in_feat, const int* ei, int Nn, int Ee,
                             const float* Wl, const float* bl, const float* Wr,
                             const float* gamma, const float* beta,
                             float* agg, float* stats, float* ss,
                             float* out, hipStream_t stream) {
    long aggN = (long)Nn * 128;
    long n4 = aggN / 4;

    zero_stats_kernel<<<1, 256, 0, stream>>>(stats);
    int initBlocks = (int)((n4 + 255) / 256);
    if (initBlocks > 4096) initBlocks = 4096;
    init_sentinel_kernel<<<initBlocks, 256, 0, stream>>>((uint4*)agg, n4);
    int sb = (int)(((long)Ee * 32 + 255) / 256);
    scatter_max_kernel<<<sb, 256, 0, stream>>>((const float4*)in_feat, ei,
                                               (unsigned*)agg, Ee);
    int ub = (int)((aggN + 255) / 256);
    if (ub > 8192) ub = 8192;
    unmap_kernel<<<ub, 256, 0, stream>>>((unsigned*)agg, aggN);
    gemm_kernel<<<(Nn + 63) / 64, 256, 0, stream>>>(agg, in_feat, Wl, Wr, bl,
                                                    out, stats, Nn);
    finalize_kernel<<<1, 128, 0, stream>>>(stats, gamma, beta, ss, 1.0f / (float)Nn);
    int bnBlocks = (int)((n4 + 255) / 256);
    if (bnBlocks > 8192) bnBlocks = 8192;
    bn_relu_kernel<<<bnBlocks, 256, 0, stream>>>((float4*)out, ss, n4);
}

extern "C" void kernel_launch(void* const* d_in, const int* in_sizes, int n_in,
                              void* d_out, int out_size, void* d_ws, size_t ws_size,
                              hipStream_t stream) {
    (void)n_in; (void)out_size;
    const float* x     = (const float*)d_in[0];
    const int*   ei    = (const int*)d_in[1];
    const float* W0_l  = (const float*)d_in[2];
    const float* b0_l  = (const float*)d_in[3];
    const float* W0_r  = (const float*)d_in[4];
    const float* g0    = (const float*)d_in[5];
    const float* be0   = (const float*)d_in[6];
    const float* W1_l  = (const float*)d_in[7];
    const float* b1_l  = (const float*)d_in[8];
    const float* W1_r  = (const float*)d_in[9];
    const float* g1    = (const float*)d_in[10];
    const float* be1   = (const float*)d_in[11];

    int Nn = in_sizes[0] / 128;
    int Ee = in_sizes[1] / 2;
    long n4 = (long)Nn * 32;                   // float4 / uint2 row-elems

    char* p = (char*)d_ws;
    unsigned short* xy16 = (unsigned short*)p;  p += (size_t)Nn * 128 * 2;  // x16, later y16
    unsigned short* agg16 = (unsigned short*)p; p += (size_t)Nn * 128 * 2;
    float* stats = (float*)p;                   p += 256 * sizeof(float);
    float* ss = (float*)p;                      p += 256 * sizeof(float);
    unsigned short* Wt0 = (unsigned short*)p;   p += 128 * 256 * 2;
    unsigned short* Wt1 = (unsigned short*)p;   p += 128 * 256 * 2;
    int* head = (int*)p;                        p += (size_t)Nn * sizeof(int);
    uint2* pair = (uint2*)p;                    p += (size_t)Ee * sizeof(uint2);
    size_t needed = (size_t)(p - (char*)d_ws);
    float* out = (float*)d_out;

    if (ws_size >= needed) {
        // ---- bf16 MFMA path ----
        int cvB = (int)((n4 + 255) / 256);
        if (cvB > 4096) cvB = 4096;
        f32_to_bf16_kernel<<<cvB, 256, 0, stream>>>((const float4*)x, (uint2*)xy16, n4);
        wt_prep_kernel<<<128, 256, 0, stream>>>(W0_l, W0_r, Wt0);
        wt_prep_kernel<<<128, 256, 0, stream>>>(W1_l, W1_r, Wt1);
        init_head_kernel<<<(Nn + 255) / 256, 256, 0, stream>>>(head, Nn);
        link_kernel<<<(Ee + 255) / 256, 256, 0, stream>>>(ei, head, pair, Ee);

        // layer 1: h1 -> d_out (scratch), y1(bf16) -> xy16 (x16 dead after gemm)
        run_layer_bf16(xy16, head, pair, Nn, Wt0, b0_l, g0, be0,
                       agg16, stats, ss, out, stream);
        int bnB = (int)((n4 + 255) / 256);
        if (bnB > 8192) bnB = 8192;
        bn_relu_tobf16_kernel<<<bnB, 256, 0, stream>>>((const float4*)out, ss,
                                                       (uint2*)xy16, n4);
        // layer 2: h2 -> d_out, final BN+ReLU in place (fp32)
        run_layer_bf16(xy16, head, pair, Nn, Wt1, b1_l, g1, be1,
                       agg16, stats, ss, out, stream);
        bn_relu_kernel<<<bnB, 256, 0, stream>>>((float4*)out, ss, n4);
    } else {
        // ---- fallback: fp32 atomic path ----
        float* agg = (float*)d_ws;
        float* fstats = (float*)((char*)d_ws + (size_t)Nn * 128 * sizeof(float));
        float* fss = fstats + 256;
        run_layer_atomic(x, ei, Nn, Ee, W0_l, b0_l, W0_r, g0, be0,
                         agg, fstats, fss, out, stream);
        run_layer_atomic(out, ei, Nn, Ee, W1_l, b1_l, W1_r, g1, be1,
                         agg, fstats, fss, out, stream);
    }
}